// Round 2
// baseline (258.567 us; speedup 1.0000x reference)
//
#include <hip/hip_runtime.h>

#define NQ 12
#define NL 4

// ---------------------------------------------------------------------------
// Compile-time tracking of the CNOT permutation as a linear map over GF(2)^12.
// ref_t[i] = mine[rho_t(i)], rho accumulates CNOTs (rho <- rho o C_q).
// sigma := rho^{-1}.  RY on qubit q (bit p = 11-q) becomes, on `mine`:
//   mine'[j] = c*mine[j] + sgn(parity(row_p(sigma) & j)) * s * mine[j ^ sigma^{-1}(e_p)]
// with sgn = +s iff parity odd (matches reference's bit-set => +s convention).
// ---------------------------------------------------------------------------
struct MaskTab {
  int mk[NL][NQ];   // pair xor-mask per (layer, qubit)   = sigma^{-1}(e_p)
  int rm[NL][NQ];   // sign parity mask per (layer, qubit) = row_p(sigma)
  int rout[NQ];     // final output sign parity mask per qubit
};

static constexpr MaskTab build_masks() {
  MaskTab T{};
  unsigned col[NQ] = {};  // col[k] = sigma(e_k)
  unsigned inv[NQ] = {};  // inv[k] = sigma^{-1}(e_k)
  for (int k = 0; k < NQ; ++k) { col[k] = 1u << k; inv[k] = 1u << k; }
  for (int l = 0; l < NL; ++l) {
    for (int q = 0; q < NQ; ++q) {
      const int p = NQ - 1 - q;
      T.mk[l][q] = (int)inv[p];
      int rm = 0;
      for (int k = 0; k < NQ; ++k) rm |= (int)(((col[k] >> p) & 1u) << k);
      T.rm[l][q] = rm;
    }
    // CNOT chain q=0..10: sigma <- C_q o sigma ; sigma^{-1} <- sigma^{-1} o C_q
    for (int q = 0; q < NQ - 1; ++q) {
      const int pc = NQ - 1 - q, pt = NQ - 2 - q;
      for (int k = 0; k < NQ; ++k) col[k] ^= ((col[k] >> pc) & 1u) << pt;
      inv[pc] ^= inv[pt];
    }
  }
  for (int q = 0; q < NQ; ++q) {
    const int p = NQ - 1 - q;
    int rm = 0;
    for (int k = 0; k < NQ; ++k) rm |= (int)(((col[k] >> p) & 1u) << k);
    T.rout[q] = rm;
  }
  return T;
}

static constexpr MaskTab MT = build_masks();

// One RY gate. State: 64 fp32 per lane; global index i = (lane<<6) | j.
// new S[i] = c*S[i] + sgn*s*S[i^MK],  sgn = +s iff parity(RM & i) odd.
template<int L, int Q>
__device__ __forceinline__ void gate(float (&s)[64], float c, float sn, int lane) {
  constexpr int MK  = MT.mk[L][Q];
  constexpr int RM  = MT.rm[L][Q];
  constexpr int MKL = (MK >> 6) & 63;  // lane-bit part of pair mask
  constexpr int MKO = MK & 63;         // register-bit part
  constexpr int RMH = (RM >> 6) & 63;
  constexpr int RMO = RM & 63;
  // fold lane parity into the sign base: odd lane-parity -> +sn, even -> -sn
  const float sl = (__popc(lane & RMH) & 1) ? sn : -sn;
  if constexpr (MKO == 0) {
    // pure cross-lane pairing: partner is same register on lane^MKL
    #pragma unroll
    for (int j = 0; j < 64; ++j) {
      float pj = __shfl_xor(s[j], MKL, 64);
      float sj = (__popc(j & RMO) & 1) ? -sl : sl;  // compile-time select of +/-
      s[j] = c * s[j] + sj * pj;
    }
  } else {
    // enumerate XOR-pairs canonically by the HIGHEST bit of MKO:
    // j0 has HB clear, partner j1 = j0 ^ MKO has HB set -> disjoint full cover
    constexpr int HB = 1 << (31 - __builtin_clz((unsigned)MKO));
    #pragma unroll
    for (int j0 = 0; j0 < 64; ++j0) {
      if ((j0 & HB) != 0) continue;  // compile-time after unroll
      const int j1 = j0 ^ MKO;
      float a = s[j0], b = s[j1];
      float pa, pb;
      if constexpr (MKL != 0) {
        pa = __shfl_xor(b, MKL, 64);
        pb = __shfl_xor(a, MKL, 64);
      } else {
        pa = b;
        pb = a;
      }
      float sa = (__popc(j0 & RMO) & 1) ? -sl : sl;
      float sb = (__popc(j1 & RMO) & 1) ? -sl : sl;
      s[j0] = c * a + sa * pa;
      s[j1] = c * b + sb * pb;
    }
  }
}

template<int L, int Q>
__device__ __forceinline__ void round_rec(float (&s)[64], const float (&c)[NQ],
                                          const float (&sn)[NQ], int lane) {
  if constexpr (Q < NQ) {
    gate<L, Q>(s, c[Q], sn[Q], lane);
    round_rec<L, Q + 1>(s, c, sn, lane);
  }
}

template<int L>
__device__ __forceinline__ void layer(float (&s)[64], const float (&ic)[NQ],
                                      const float (&is)[NQ],
                                      const float* __restrict__ thetas, int lane) {
  float tc[NQ], ts[NQ];
  #pragma unroll
  for (int q = 0; q < NQ; ++q) {
    __sincosf(0.5f * thetas[L * NQ + q], &ts[q], &tc[q]);
  }
  round_rec<L, 0>(s, ic, is, lane);   // input-angle round (per-batch angles)
  round_rec<L, 0>(s, tc, ts, lane);   // theta round (shared angles)
  // CNOT chain: absorbed into the next layer's masks at compile time (free)
}

__global__ __launch_bounds__(256) void vqc_kernel(const float* __restrict__ ang,
                                                  const float* __restrict__ thetas,
                                                  float* __restrict__ out, int B) {
  const int tid  = blockIdx.x * blockDim.x + threadIdx.x;
  const int w    = tid >> 6;   // batch element = wave
  const int lane = tid & 63;
  if (w >= B) return;

  // per-batch input-angle cos/sin, reused by all 4 layers
  float ic[NQ], is[NQ];
  #pragma unroll
  for (int q = 0; q < NQ; ++q) {
    __sincosf(0.5f * ang[w * NQ + q], &is[q], &ic[q]);
  }

  // state: |0...0>
  float s[64];
  #pragma unroll
  for (int j = 0; j < 64; ++j) s[j] = 0.0f;
  if (lane == 0) s[0] = 1.0f;

  layer<0>(s, ic, is, thetas, lane);
  layer<1>(s, ic, is, thetas, lane);
  layer<2>(s, ic, is, thetas, lane);
  layer<3>(s, ic, is, thetas, lane);

  // probabilities
  #pragma unroll
  for (int j = 0; j < 64; ++j) s[j] *= s[j];

  // out[w][q] = sum_i (-1)^parity(rout_q & i) * probs[i]
  #pragma unroll
  for (int q = 0; q < NQ; ++q) {
    const int RM  = MT.rout[q];
    const int RMH = (RM >> 6) & 63;
    const int RMO = RM & 63;
    float acc = 0.0f;
    #pragma unroll
    for (int j = 0; j < 64; ++j) {
      acc += (__popc(j & RMO) & 1) ? -s[j] : s[j];
    }
    if (__popc(lane & RMH) & 1) acc = -acc;
    #pragma unroll
    for (int m = 32; m >= 1; m >>= 1) acc += __shfl_xor(acc, m, 64);
    if (lane == 0) out[w * NQ + q] = acc;
  }
}

extern "C" void kernel_launch(void* const* d_in, const int* in_sizes, int n_in,
                              void* d_out, int out_size, void* d_ws, size_t ws_size,
                              hipStream_t stream) {
  const float* ang    = (const float*)d_in[0];   // (B, 12) fp32
  const float* thetas = (const float*)d_in[1];   // (4, 12) fp32
  float* out          = (float*)d_out;           // (B, 12) fp32
  const int B = in_sizes[0] / NQ;
  const int threads = 256;                        // 4 waves / block
  const int blocks = (B * 64 + threads - 1) / threads;
  hipLaunchKernelGGL(vqc_kernel, dim3(blocks), dim3(threads), 0, stream,
                     ang, thetas, out, B);
}

// Round 3
// 126.316 us; speedup vs baseline: 2.0470x; 2.0470x over previous
//
#include <hip/hip_runtime.h>

#define NQ 12
#define NL 4

// ---------------------------------------------------------------------------
// Compile-time tracking of the CNOT permutation as a linear map over GF(2)^12.
// RY on qubit q (bit p = 11-q) becomes, on stored state:
//   mine'[j] = c*mine[j] + sgn(parity(rm & j)) * s * mine[j ^ mk]
// with sgn = +s iff parity odd.
//
// FUSION: within a layer, the input-angle round and theta round are 24 RY
// gates with no CNOT between them. RY gates on distinct qubits commute, and
// RY(a)RY(b) = RY(a+b) on the same qubit => one fused round of 12 gates with
// angles input[q] + theta[l][q]. Halves gate count and shuffle traffic.
// ---------------------------------------------------------------------------
struct MaskTab {
  int mk[NL][NQ];   // pair xor-mask per (layer, qubit)   = sigma^{-1}(e_p)
  int rm[NL][NQ];   // sign parity mask per (layer, qubit) = row_p(sigma)
  int rout[NQ];     // final output sign parity mask per qubit
};

static constexpr MaskTab build_masks() {
  MaskTab T{};
  unsigned col[NQ] = {};  // col[k] = sigma(e_k)
  unsigned inv[NQ] = {};  // inv[k] = sigma^{-1}(e_k)
  for (int k = 0; k < NQ; ++k) { col[k] = 1u << k; inv[k] = 1u << k; }
  for (int l = 0; l < NL; ++l) {
    for (int q = 0; q < NQ; ++q) {
      const int p = NQ - 1 - q;
      T.mk[l][q] = (int)inv[p];
      int rm = 0;
      for (int k = 0; k < NQ; ++k) rm |= (int)(((col[k] >> p) & 1u) << k);
      T.rm[l][q] = rm;
    }
    // CNOT chain q=0..10: sigma <- C_q o sigma ; sigma^{-1} <- sigma^{-1} o C_q
    for (int q = 0; q < NQ - 1; ++q) {
      const int pc = NQ - 1 - q, pt = NQ - 2 - q;
      for (int k = 0; k < NQ; ++k) col[k] ^= ((col[k] >> pc) & 1u) << pt;
      inv[pc] ^= inv[pt];
    }
  }
  for (int q = 0; q < NQ; ++q) {
    const int p = NQ - 1 - q;
    int rm = 0;
    for (int k = 0; k < NQ; ++k) rm |= (int)(((col[k] >> p) & 1u) << k);
    T.rout[q] = rm;
  }
  return T;
}

static constexpr MaskTab MT = build_masks();

// One RY gate. State: 64 fp32 per lane; global index i = (lane<<6) | j.
// new S[i] = c*S[i] + sgn*s*S[i^MK],  sgn = +s iff parity(RM & i) odd.
template<int L, int Q>
__device__ __forceinline__ void gate(float (&s)[64], float c, float sn, int lane) {
  constexpr int MK  = MT.mk[L][Q];
  constexpr int RM  = MT.rm[L][Q];
  constexpr int MKL = (MK >> 6) & 63;  // lane-bit part of pair mask
  constexpr int MKO = MK & 63;         // register-bit part
  constexpr int RMH = (RM >> 6) & 63;
  constexpr int RMO = RM & 63;
  // fold lane parity into the sign base: odd lane-parity -> +sn, even -> -sn
  const float sl = (__popc(lane & RMH) & 1) ? sn : -sn;
  if constexpr (MKO == 0) {
    // pure cross-lane pairing: partner is same register on lane^MKL
    #pragma unroll
    for (int j = 0; j < 64; ++j) {
      float pj = __shfl_xor(s[j], MKL, 64);
      float sj = (__popc(j & RMO) & 1) ? -sl : sl;  // compile-time +/- select
      s[j] = c * s[j] + sj * pj;
    }
  } else {
    // enumerate XOR-pairs canonically by the HIGHEST bit of MKO:
    // j0 has HB clear, partner j1 = j0 ^ MKO has HB set -> disjoint full cover
    constexpr int HB = 1 << (31 - __builtin_clz((unsigned)MKO));
    #pragma unroll
    for (int j0 = 0; j0 < 64; ++j0) {
      if ((j0 & HB) != 0) continue;  // compile-time after unroll
      const int j1 = j0 ^ MKO;
      float a = s[j0], b = s[j1];
      float pa, pb;
      if constexpr (MKL != 0) {
        pa = __shfl_xor(b, MKL, 64);
        pb = __shfl_xor(a, MKL, 64);
      } else {
        pa = b;
        pb = a;
      }
      float sa = (__popc(j0 & RMO) & 1) ? -sl : sl;
      float sb = (__popc(j1 & RMO) & 1) ? -sl : sl;
      s[j0] = c * a + sa * pa;
      s[j1] = c * b + sb * pb;
    }
  }
}

template<int L, int Q>
__device__ __forceinline__ void round_rec(float (&s)[64], const float (&c)[NQ],
                                          const float (&sn)[NQ], int lane) {
  if constexpr (Q < NQ) {
    gate<L, Q>(s, c[Q], sn[Q], lane);
    round_rec<L, Q + 1>(s, c, sn, lane);
  }
}

// One layer = ONE fused round with angles (input[q] + theta[l][q]).
template<int L>
__device__ __forceinline__ void layer(float (&s)[64], const float (&a)[NQ],
                                      const float* __restrict__ thetas, int lane) {
  float c[NQ], sn[NQ];
  #pragma unroll
  for (int q = 0; q < NQ; ++q) {
    __sincosf(0.5f * (a[q] + thetas[L * NQ + q]), &sn[q], &c[q]);
  }
  round_rec<L, 0>(s, c, sn, lane);
  // CNOT chain: absorbed into the next layer's masks at compile time (free)
}

__global__ __launch_bounds__(256) void vqc_kernel(const float* __restrict__ ang,
                                                  const float* __restrict__ thetas,
                                                  float* __restrict__ out, int B) {
  const int tid  = blockIdx.x * blockDim.x + threadIdx.x;
  const int w    = tid >> 6;   // batch element = wave
  const int lane = tid & 63;
  if (w >= B) return;

  // per-batch input angles, reused by all 4 layers
  float a[NQ];
  #pragma unroll
  for (int q = 0; q < NQ; ++q) a[q] = ang[w * NQ + q];

  // state: |0...0>
  float s[64];
  #pragma unroll
  for (int j = 0; j < 64; ++j) s[j] = 0.0f;
  if (lane == 0) s[0] = 1.0f;

  layer<0>(s, a, thetas, lane);
  layer<1>(s, a, thetas, lane);
  layer<2>(s, a, thetas, lane);
  layer<3>(s, a, thetas, lane);

  // probabilities
  #pragma unroll
  for (int j = 0; j < 64; ++j) s[j] *= s[j];

  // out[w][q] = sum_i (-1)^parity(rout_q & i) * probs[i]
  #pragma unroll
  for (int q = 0; q < NQ; ++q) {
    const int RM  = MT.rout[q];
    const int RMH = (RM >> 6) & 63;
    const int RMO = RM & 63;
    float acc = 0.0f;
    #pragma unroll
    for (int j = 0; j < 64; ++j) {
      acc += (__popc(j & RMO) & 1) ? -s[j] : s[j];
    }
    if (__popc(lane & RMH) & 1) acc = -acc;
    #pragma unroll
    for (int m = 32; m >= 1; m >>= 1) acc += __shfl_xor(acc, m, 64);
    if (lane == 0) out[w * NQ + q] = acc;
  }
}

extern "C" void kernel_launch(void* const* d_in, const int* in_sizes, int n_in,
                              void* d_out, int out_size, void* d_ws, size_t ws_size,
                              hipStream_t stream) {
  const float* ang    = (const float*)d_in[0];   // (B, 12) fp32
  const float* thetas = (const float*)d_in[1];   // (4, 12) fp32
  float* out          = (float*)d_out;           // (B, 12) fp32
  const int B = in_sizes[0] / NQ;
  const int threads = 256;                        // 4 waves / block
  const int blocks = (B * 64 + threads - 1) / threads;
  hipLaunchKernelGGL(vqc_kernel, dim3(blocks), dim3(threads), 0, stream,
                     ang, thetas, out, B);
}

// Round 4
// 94.142 us; speedup vs baseline: 2.7466x; 1.3418x over previous
//
#include <hip/hip_runtime.h>

#define NQ 12
#define NL 4

// ---------------------------------------------------------------------------
// Compile-time CNOT tracking as a GF(2) linear map (see round-2 comments).
// RY(l,q): mine'[j] = c*mine[j] + sgn(parity(rm&j))*s*mine[j^mk], + iff odd.
// Layer = ONE fused round, angles input[q]+theta[l][q] (RY(a)RY(b)=RY(a+b)).
// NEW: layer 0 on |0..0> is a tensor-product state -> built directly (no gates).
// NEW: cross-lane gates use VALU DPP / permlane16/32_swap instead of DS
//      shuffles where the lane-mask allows; only 7 gates remain on DS pipe.
// ---------------------------------------------------------------------------
struct MaskTab {
  int mk[NL][NQ];
  int rm[NL][NQ];
  int rout[NQ];
};

static constexpr MaskTab build_masks() {
  MaskTab T{};
  unsigned col[NQ] = {};
  unsigned inv[NQ] = {};
  for (int k = 0; k < NQ; ++k) { col[k] = 1u << k; inv[k] = 1u << k; }
  for (int l = 0; l < NL; ++l) {
    for (int q = 0; q < NQ; ++q) {
      const int p = NQ - 1 - q;
      T.mk[l][q] = (int)inv[p];
      int rm = 0;
      for (int k = 0; k < NQ; ++k) rm |= (int)(((col[k] >> p) & 1u) << k);
      T.rm[l][q] = rm;
    }
    for (int q = 0; q < NQ - 1; ++q) {
      const int pc = NQ - 1 - q, pt = NQ - 2 - q;
      for (int k = 0; k < NQ; ++k) col[k] ^= ((col[k] >> pc) & 1u) << pt;
      inv[pc] ^= inv[pt];
    }
  }
  for (int q = 0; q < NQ; ++q) {
    const int p = NQ - 1 - q;
    int rm = 0;
    for (int k = 0; k < NQ; ++k) rm |= (int)(((col[k] >> p) & 1u) << k);
    T.rout[q] = rm;
  }
  return T;
}

static constexpr MaskTab MT = build_masks();

// ---------------- VALU cross-lane helpers ----------------
// DPP ctrl encodings: quad_perm xor1/2/3, row_ror:8 (=xor8), half_mirror(=xor7),
// row_mirror(=xor15).
template <int CTRL>
__device__ __forceinline__ float dpp_mov(float x) {
  return __int_as_float(
      __builtin_amdgcn_update_dpp(0, __float_as_int(x), CTRL, 0xF, 0xF, false));
}

__device__ __forceinline__ constexpr int dpp_ctrl_for(int d) {
  // d in {1,2,3,7,8,15}
  return d == 1 ? 0xB1 : d == 2 ? 0x4E : d == 3 ? 0x1B
       : d == 7 ? 0x141 : d == 8 ? 0x128 : 0x140;
}
__device__ __forceinline__ constexpr bool dpp_ok(int d) {
  return d == 1 || d == 2 || d == 3 || d == 7 || d == 8 || d == 15;
}

// partner fetch with optional DPP xor-d (d==0 -> identity)
template <int D>
__device__ __forceinline__ float dapply(float x) {
  if constexpr (D == 0) return x;
  else return dpp_mov<dpp_ctrl_for(D)>(x);
}

// v_permlane32_swap_b32: a' = [a_lo|b_lo], b' = [a_hi|b_hi]
__device__ __forceinline__ void plane32_swap(float &a, float &b) {
  asm("v_permlane32_swap_b32 %0, %1" : "+v"(a), "+v"(b));
}
// v_permlane16_swap_b32: a' = [a_r0,b_r0,a_r2,b_r2], b' = [a_r1,b_r1,a_r3,b_r3]
__device__ __forceinline__ void plane16_swap(float &a, float &b) {
  asm("v_permlane16_swap_b32 %0, %1" : "+v"(a), "+v"(b));
}

// ---------------- one RY gate ----------------
// new S[i] = c*S[i] + sgn*s*S[i^MK], sgn=+s iff parity(RM&i) odd, i=(lane<<6)|j
template <int L, int Q>
__device__ __forceinline__ void gate(float (&s)[64], float c, float sn, int lane) {
  constexpr int MK  = MT.mk[L][Q];
  constexpr int RM  = MT.rm[L][Q];
  constexpr int MKL = (MK >> 6) & 63;
  constexpr int MKO = MK & 63;
  constexpr int RMH = (RM >> 6) & 63;
  constexpr int RMO = RM & 63;

  if constexpr (MKL == 0) {
    // pure register butterfly
    const float sl = (__popc(lane & RMH) & 1) ? sn : -sn;
    constexpr int HB = 1 << (31 - __builtin_clz((unsigned)MKO));
    #pragma unroll
    for (int j0 = 0; j0 < 64; ++j0) {
      if ((j0 & HB) != 0) continue;
      const int j1 = j0 ^ MKO;
      float a = s[j0], b = s[j1];
      float sa = (__popc(j0 & RMO) & 1) ? -sl : sl;
      float sb = (__popc(j1 & RMO) & 1) ? -sl : sl;
      s[j0] = c * a + sa * b;
      s[j1] = c * b + sb * a;
    }
  } else if constexpr (dpp_ok(MKL)) {
    // DPP-expressible lane xor (VALU pipe), any MKO
    const float sl = (__popc(lane & RMH) & 1) ? sn : -sn;
    if constexpr (MKO == 0) {
      #pragma unroll
      for (int j = 0; j < 64; ++j) {
        float sj = (__popc(j & RMO) & 1) ? -sl : sl;
        s[j] = c * s[j] + sj * dapply<MKL>(s[j]);
      }
    } else {
      constexpr int HB = 1 << (31 - __builtin_clz((unsigned)MKO));
      #pragma unroll
      for (int j0 = 0; j0 < 64; ++j0) {
        if ((j0 & HB) != 0) continue;
        const int j1 = j0 ^ MKO;
        float a = s[j0], b = s[j1];
        float sa = (__popc(j0 & RMO) & 1) ? -sl : sl;
        float sb = (__popc(j1 & RMO) & 1) ? -sl : sl;
        s[j0] = c * a + sa * dapply<MKL>(b);
        s[j1] = c * b + sb * dapply<MKL>(a);
      }
    }
  } else if constexpr (MKO == 0 && (MKL & 48) == 32 && dpp_ok(MKL & 15)) {
    // lane xor = 32|d : permlane32_swap pairs (j, j+1); reg-bit0 <-> lane-bit5
    constexpr int D = MKL & 15;
    constexpr int RHO = (RMH & 31) | ((RMO & 1) << 5);
    constexpr int VF = (RMH >> 5) & 1;  // sign flip for the v-word (lam5=1)
    const float sgn = (__popc(lane & RHO) & 1) ? sn : -sn;
    #pragma unroll
    for (int j = 0; j < 64; j += 2) {
      float a = s[j], b = s[j + 1];
      plane32_swap(a, b);  // a=u(lam5=0), b=v(lam5=1)
      constexpr bool FB0 = false;  // placeholder; per-j below
      (void)sizeof(FB0);
      const bool fb = (__popc(j & RMO) & 1);  // j even; bit0 via lane mask
      float su = fb ? -sgn : sgn;
      float sv = (fb ^ (VF != 0)) ? -sgn : sgn;
      float nu = c * a + su * dapply<D>(b);
      float nv = c * b + sv * dapply<D>(a);
      plane32_swap(nu, nv);
      s[j] = nu; s[j + 1] = nv;
    }
  } else if constexpr (MKO == 0 && (MKL & 48) == 16 && dpp_ok(MKL & 15)) {
    // lane xor = 16|d : permlane16_swap pairs (j, j+1); reg-bit0 <-> lane-bit4
    constexpr int D = MKL & 15;
    constexpr int RHO = (RMH & 0b101111) | ((RMO & 1) << 4);
    constexpr int VF = (RMH >> 4) & 1;  // sign flip for lam4=1 word
    const float sgn = (__popc(lane & RHO) & 1) ? sn : -sn;
    #pragma unroll
    for (int j = 0; j < 64; j += 2) {
      float a = s[j], b = s[j + 1];
      plane16_swap(a, b);  // a: lam4=0, b: lam4=1
      const bool fb = (__popc(j & RMO) & 1);
      float su = fb ? -sgn : sgn;
      float sv = (fb ^ (VF != 0)) ? -sgn : sgn;
      float nu = c * a + su * dapply<D>(b);
      float nv = c * b + sv * dapply<D>(a);
      plane16_swap(nu, nv);
      s[j] = nu; s[j + 1] = nv;
    }
  } else if constexpr (MKO == 0 && (MKL & 48) == 48 &&
                       ((MKL & 15) == 0 || dpp_ok(MKL & 15))) {
    // lane xor = 48|d : quad of regs; bit0<->lane5 (swap32), bit1<->lane4 (swap16)
    constexpr int D = MKL & 15;
    constexpr int RHO = (RMH & 15) | ((RMO & 1) << 5) | ((RMO & 2) << 3);
    constexpr int H4 = (RMH >> 4) & 1;
    constexpr int H5 = (RMH >> 5) & 1;
    const float sgn = (__popc(lane & RHO) & 1) ? sn : -sn;
    #pragma unroll
    for (int j = 0; j < 64; j += 4) {
      float a0 = s[j], a1 = s[j + 1], a2 = s[j + 2], a3 = s[j + 3];
      plane32_swap(a0, a1);  // a0=u01, a1=v01
      plane32_swap(a2, a3);  // a2=u23, a3=v23
      plane16_swap(a0, a2);  // a0=(l5=0,l4=0), a2=(0,1)
      plane16_swap(a1, a3);  // a1=(1,0),       a3=(1,1)
      const bool fb = (__popc(j & RMO) & 1);
      float s00 = (fb)                      ? -sgn : sgn;
      float s01 = (fb ^ (H4 != 0))          ? -sgn : sgn;
      float s10 = (fb ^ (H5 != 0))          ? -sgn : sgn;
      float s11 = (fb ^ ((H4 ^ H5) != 0))   ? -sgn : sgn;
      float n0 = c * a0 + s00 * dapply<D>(a3);  // (0,0) <-> (1,1)
      float n3 = c * a3 + s11 * dapply<D>(a0);
      float n2 = c * a2 + s01 * dapply<D>(a1);  // (0,1) <-> (1,0)
      float n1 = c * a1 + s10 * dapply<D>(a2);
      plane16_swap(n0, n2);
      plane16_swap(n1, n3);
      plane32_swap(n0, n1);
      plane32_swap(n2, n3);
      s[j] = n0; s[j + 1] = n1; s[j + 2] = n2; s[j + 3] = n3;
    }
  } else {
    // DS fallback (masks 12,6,20,10,5,60,30): generic shuffle path
    const float sl = (__popc(lane & RMH) & 1) ? sn : -sn;
    if constexpr (MKO == 0) {
      #pragma unroll
      for (int j = 0; j < 64; ++j) {
        float pj = __shfl_xor(s[j], MKL, 64);
        float sj = (__popc(j & RMO) & 1) ? -sl : sl;
        s[j] = c * s[j] + sj * pj;
      }
    } else {
      constexpr int HB = 1 << (31 - __builtin_clz((unsigned)MKO));
      #pragma unroll
      for (int j0 = 0; j0 < 64; ++j0) {
        if ((j0 & HB) != 0) continue;
        const int j1 = j0 ^ MKO;
        float a = s[j0], b = s[j1];
        float pa = __shfl_xor(b, MKL, 64);
        float pb = __shfl_xor(a, MKL, 64);
        float sa = (__popc(j0 & RMO) & 1) ? -sl : sl;
        float sb = (__popc(j1 & RMO) & 1) ? -sl : sl;
        s[j0] = c * a + sa * pa;
        s[j1] = c * b + sb * pb;
      }
    }
  }
}

template <int L, int Q>
__device__ __forceinline__ void round_rec(float (&s)[64], const float (&c)[NQ],
                                          const float (&sn)[NQ], int lane) {
  if constexpr (Q < NQ) {
    gate<L, Q>(s, c[Q], sn[Q], lane);
    round_rec<L, Q + 1>(s, c, sn, lane);
  }
}

template <int L>
__device__ __forceinline__ void layer(float (&s)[64], const float (&a)[NQ],
                                      const float* __restrict__ thetas, int lane) {
  float c[NQ], sn[NQ];
  #pragma unroll
  for (int q = 0; q < NQ; ++q) {
    __sincosf(0.5f * (a[q] + thetas[L * NQ + q]), &sn[q], &c[q]);
  }
  round_rec<L, 0>(s, c, sn, lane);
}

__global__ __launch_bounds__(256) void vqc_kernel(const float* __restrict__ ang,
                                                  const float* __restrict__ thetas,
                                                  float* __restrict__ out, int B) {
  const int tid  = blockIdx.x * blockDim.x + threadIdx.x;
  const int w    = tid >> 6;
  const int lane = tid & 63;
  if (w >= B) return;

  float a[NQ];
  #pragma unroll
  for (int q = 0; q < NQ; ++q) a[q] = ang[w * NQ + q];

  // ---- layer 0 on |0..0> is a product state: build directly ----
  float c0[NQ], s0[NQ];
  #pragma unroll
  for (int q = 0; q < NQ; ++q) {
    __sincosf(0.5f * (a[q] + thetas[q]), &s0[q], &c0[q]);
  }
  // lane factor: lane bit k == index bit 6+k == qubit 5-k
  float flane = 1.0f;
  #pragma unroll
  for (int k = 0; k < 6; ++k) {
    flane *= ((lane >> k) & 1) ? s0[5 - k] : c0[5 - k];
  }
  float s[64];
  s[0] = flane;
  // register doubling: reg bit b == index bit b == qubit 11-b
  #pragma unroll
  for (int b = 0; b < 6; ++b) {
    const int W = 1 << b;
    #pragma unroll
    for (int j = 0; j < 64; ++j) {
      if (j >= W) continue;
      s[j + W] = s[j] * s0[11 - b];
      s[j]     = s[j] * c0[11 - b];
    }
  }

  layer<1>(s, a, thetas, lane);
  layer<2>(s, a, thetas, lane);
  layer<3>(s, a, thetas, lane);

  #pragma unroll
  for (int j = 0; j < 64; ++j) s[j] *= s[j];

  #pragma unroll
  for (int q = 0; q < NQ; ++q) {
    const int RM  = MT.rout[q];
    const int RMH = (RM >> 6) & 63;
    const int RMO = RM & 63;
    float acc = 0.0f;
    #pragma unroll
    for (int j = 0; j < 64; ++j) {
      acc += (__popc(j & RMO) & 1) ? -s[j] : s[j];
    }
    if (__popc(lane & RMH) & 1) acc = -acc;
    #pragma unroll
    for (int m = 32; m >= 1; m >>= 1) acc += __shfl_xor(acc, m, 64);
    if (lane == 0) out[w * NQ + q] = acc;
  }
}

extern "C" void kernel_launch(void* const* d_in, const int* in_sizes, int n_in,
                              void* d_out, int out_size, void* d_ws, size_t ws_size,
                              hipStream_t stream) {
  const float* ang    = (const float*)d_in[0];
  const float* thetas = (const float*)d_in[1];
  float* out          = (float*)d_out;
  const int B = in_sizes[0] / NQ;
  const int threads = 256;
  const int blocks = (B * 64 + threads - 1) / threads;
  hipLaunchKernelGGL(vqc_kernel, dim3(blocks), dim3(threads), 0, stream,
                     ang, thetas, out, B);
}

// Round 5
// 71.612 us; speedup vs baseline: 3.6106x; 1.3146x over previous
//
#include <hip/hip_runtime.h>

#define NQ 12
#define NL 4

// ---------------------------------------------------------------------------
// Compile-time CNOT tracking as a GF(2) linear map (rounds 1-4, verified).
// RY(l,q): mine'[j] = c*(mine[j] + tau_j * mine[j^mk]), tau_j = +tan iff
// parity(rm&j) odd else -tan.  The uniform c factors accumulate into Ctot;
// outputs are scaled by Ctot^2 at the end (probs are quadratic in the state).
// Layer = ONE fused round (RY(a)RY(b)=RY(a+b)); layer 0 = product state.
// ---------------------------------------------------------------------------
struct MaskTab {
  int mk[NL][NQ];
  int rm[NL][NQ];
  int rout[NQ];
};

static constexpr MaskTab build_masks() {
  MaskTab T{};
  unsigned col[NQ] = {};
  unsigned inv[NQ] = {};
  for (int k = 0; k < NQ; ++k) { col[k] = 1u << k; inv[k] = 1u << k; }
  for (int l = 0; l < NL; ++l) {
    for (int q = 0; q < NQ; ++q) {
      const int p = NQ - 1 - q;
      T.mk[l][q] = (int)inv[p];
      int rm = 0;
      for (int k = 0; k < NQ; ++k) rm |= (int)(((col[k] >> p) & 1u) << k);
      T.rm[l][q] = rm;
    }
    for (int q = 0; q < NQ - 1; ++q) {
      const int pc = NQ - 1 - q, pt = NQ - 2 - q;
      for (int k = 0; k < NQ; ++k) col[k] ^= ((col[k] >> pc) & 1u) << pt;
      inv[pc] ^= inv[pt];
    }
  }
  for (int q = 0; q < NQ; ++q) {
    const int p = NQ - 1 - q;
    int rm = 0;
    for (int k = 0; k < NQ; ++k) rm |= (int)(((col[k] >> p) & 1u) << k);
    T.rout[q] = rm;
  }
  return T;
}

static constexpr MaskTab MT = build_masks();

// ---------------- cross-lane helpers ----------------
template <int CTRL>
__device__ __forceinline__ float dpp_mov(float x) {
  return __int_as_float(
      __builtin_amdgcn_update_dpp(0, __float_as_int(x), CTRL, 0xF, 0xF, false));
}
__device__ __forceinline__ constexpr int dpp_ctrl_for(int d) {
  // d in {1,2,3,7,8,15}: quad_perm xor1/2/3, row_half_mirror, row_ror:8, row_mirror
  return d == 1 ? 0xB1 : d == 2 ? 0x4E : d == 3 ? 0x1B
       : d == 7 ? 0x141 : d == 8 ? 0x128 : 0x140;
}
__device__ __forceinline__ constexpr bool dpp_ok(int d) {
  return d == 1 || d == 2 || d == 3 || d == 7 || d == 8 || d == 15;
}
template <int PAT>
__device__ __forceinline__ float ds_swz(float x) {
  return __int_as_float(__builtin_amdgcn_ds_swizzle(__float_as_int(x), PAT));
}
__device__ __forceinline__ float bperm(int idx_bytes, float x) {
  return __int_as_float(__builtin_amdgcn_ds_bpermute(idx_bytes, __float_as_int(x)));
}

// ---------------- one RY gate (tan form: 1 FMA per element) ----------------
template <int L, int Q>
__device__ __forceinline__ void gate(float (&s)[64], float t, int lane, int lane4) {
  constexpr int MK  = MT.mk[L][Q];
  constexpr int RM  = MT.rm[L][Q];
  constexpr int MKL = (MK >> 6) & 63;
  constexpr int MKO = MK & 63;
  constexpr int RMH = (RM >> 6) & 63;
  constexpr int RMO = RM & 63;
  // fold lane parity: odd -> +t, even -> -t (round-2 verified convention)
  const float tl = (__popc(lane & RMH) & 1) ? t : -t;

  if constexpr (MKL == 0) {
    // pure register butterfly: 2 FMA per pair (signs fold into VOP3 neg mod)
    constexpr int HB = 1 << (31 - __builtin_clz((unsigned)MKO));
    #pragma unroll
    for (int j0 = 0; j0 < 64; ++j0) {
      if (j0 & HB) continue;
      const int j1 = j0 ^ MKO;
      const float a = s[j0], b = s[j1];
      s[j0] = fmaf((__popc(j0 & RMO) & 1) ? -tl : tl, b, a);
      s[j1] = fmaf((__popc(j1 & RMO) & 1) ? -tl : tl, a, b);
    }
  } else if constexpr (dpp_ok(MKL)) {
    // VALU DPP partner fetch
    constexpr int CT = dpp_ctrl_for(MKL);
    if constexpr (MKO == 0) {
      #pragma unroll
      for (int j = 0; j < 64; ++j) {
        const float p = dpp_mov<CT>(s[j]);
        s[j] = fmaf((__popc(j & RMO) & 1) ? -tl : tl, p, s[j]);
      }
    } else {
      constexpr int HB = 1 << (31 - __builtin_clz((unsigned)MKO));
      #pragma unroll
      for (int j0 = 0; j0 < 64; ++j0) {
        if (j0 & HB) continue;
        const int j1 = j0 ^ MKO;
        const float pa = dpp_mov<CT>(s[j1]);
        const float pb = dpp_mov<CT>(s[j0]);
        s[j0] = fmaf((__popc(j0 & RMO) & 1) ? -tl : tl, pa, s[j0]);
        s[j1] = fmaf((__popc(j1 & RMO) & 1) ? -tl : tl, pb, s[j1]);
      }
    }
  } else if constexpr (MKL <= 31) {
    // DS pipe: ds_swizzle xor-mode (no VALU address math); DS pipe is idle
    constexpr int PAT = (MKL << 10) | 0x1F;
    if constexpr (MKO == 0) {
      #pragma unroll
      for (int j = 0; j < 64; ++j) {
        const float p = ds_swz<PAT>(s[j]);
        s[j] = fmaf((__popc(j & RMO) & 1) ? -tl : tl, p, s[j]);
      }
    } else {
      constexpr int HB = 1 << (31 - __builtin_clz((unsigned)MKO));
      #pragma unroll
      for (int j0 = 0; j0 < 64; ++j0) {
        if (j0 & HB) continue;
        const int j1 = j0 ^ MKO;
        const float pa = ds_swz<PAT>(s[j1]);
        const float pb = ds_swz<PAT>(s[j0]);
        s[j0] = fmaf((__popc(j0 & RMO) & 1) ? -tl : tl, pa, s[j0]);
        s[j1] = fmaf((__popc(j1 & RMO) & 1) ? -tl : tl, pb, s[j1]);
      }
    }
  } else {
    // lane-xor crosses the 32-lane boundary: ds_bpermute, 1 shared index
    const int idx = lane4 ^ (MKL << 2);
    if constexpr (MKO == 0) {
      #pragma unroll
      for (int j = 0; j < 64; ++j) {
        const float p = bperm(idx, s[j]);
        s[j] = fmaf((__popc(j & RMO) & 1) ? -tl : tl, p, s[j]);
      }
    } else {
      constexpr int HB = 1 << (31 - __builtin_clz((unsigned)MKO));
      #pragma unroll
      for (int j0 = 0; j0 < 64; ++j0) {
        if (j0 & HB) continue;
        const int j1 = j0 ^ MKO;
        const float pa = bperm(idx, s[j1]);
        const float pb = bperm(idx, s[j0]);
        s[j0] = fmaf((__popc(j0 & RMO) & 1) ? -tl : tl, pa, s[j0]);
        s[j1] = fmaf((__popc(j1 & RMO) & 1) ? -tl : tl, pb, s[j1]);
      }
    }
  }
}

template <int L, int Q>
__device__ __forceinline__ void round_rec(float (&s)[64], const float (&t)[NQ],
                                          int lane, int lane4) {
  if constexpr (Q < NQ) {
    gate<L, Q>(s, t[Q], lane, lane4);
    round_rec<L, Q + 1>(s, t, lane, lane4);
  }
}

// one layer in tan form; returns the layer's cosine product
template <int L>
__device__ __forceinline__ float layer_t(float (&s)[64], const float (&a)[NQ],
                                         const float* __restrict__ thetas,
                                         int lane, int lane4) {
  const float4 T0 = *(const float4*)(thetas + L * NQ);
  const float4 T1 = *(const float4*)(thetas + L * NQ + 4);
  const float4 T2 = *(const float4*)(thetas + L * NQ + 8);
  const float th[NQ] = {T0.x, T0.y, T0.z, T0.w, T1.x, T1.y, T1.z, T1.w,
                        T2.x, T2.y, T2.z, T2.w};
  float t[NQ];
  float C = 1.0f;
  #pragma unroll
  for (int q = 0; q < NQ; ++q) {
    float sn, cs;
    __sincosf(0.5f * (a[q] + th[q]), &sn, &cs);
    t[q] = __fdividef(sn, cs);
    C *= cs;
  }
  round_rec<L, 0>(s, t, lane, lane4);
  return C;
}

// epilogue: out[Q] = Ctot^2 * sum_i (-1)^parity(rout&i) * y-transform of probs
template <int Q>
__device__ __forceinline__ void epi_rec(const float (&y)[64], float Csq,
                                        int lane, int lane4,
                                        float* __restrict__ out, int w) {
  if constexpr (Q < NQ) {
    constexpr int RM  = MT.rout[Q];
    constexpr int RMH = (RM >> 6) & 63;
    constexpr int RMO = RM & 63;
    float v = y[RMO];  // register-WHT coefficient (odd parity -> minus, matches)
    if constexpr (RMH != 0) {
      v = (__popc(lane & RMH) & 1) ? -v : v;
    }
    v += ds_swz<(1 << 10) | 0x1F>(v);
    v += ds_swz<(2 << 10) | 0x1F>(v);
    v += ds_swz<(4 << 10) | 0x1F>(v);
    v += ds_swz<(8 << 10) | 0x1F>(v);
    v += ds_swz<(16 << 10) | 0x1F>(v);
    v += bperm(lane4 ^ 128, v);
    if (lane == 0) out[w * NQ + Q] = v * Csq;
    epi_rec<Q + 1>(y, Csq, lane, lane4, out, w);
  }
}

__global__ __launch_bounds__(256, 2) void vqc_kernel(const float* __restrict__ ang,
                                                     const float* __restrict__ thetas,
                                                     float* __restrict__ out, int B) {
  const int tid   = blockIdx.x * blockDim.x + threadIdx.x;
  const int w     = tid >> 6;
  const int lane  = tid & 63;
  const int lane4 = lane << 2;
  if (w >= B) return;

  const float4 A0 = *(const float4*)(ang + w * NQ);
  const float4 A1 = *(const float4*)(ang + w * NQ + 4);
  const float4 A2 = *(const float4*)(ang + w * NQ + 8);
  const float a[NQ] = {A0.x, A0.y, A0.z, A0.w, A1.x, A1.y, A1.z, A1.w,
                       A2.x, A2.y, A2.z, A2.w};

  // ---- layer 0 on |0..0>: product state, built directly (round-4 verified) ----
  float c0[NQ], s0[NQ];
  #pragma unroll
  for (int q = 0; q < NQ; ++q) {
    __sincosf(0.5f * (a[q] + thetas[q]), &s0[q], &c0[q]);
  }
  float flane = 1.0f;
  #pragma unroll
  for (int k = 0; k < 6; ++k) {
    flane *= ((lane >> k) & 1) ? s0[5 - k] : c0[5 - k];
  }
  float s[64];
  s[0] = flane;
  #pragma unroll
  for (int b = 0; b < 6; ++b) {
    const int W = 1 << b;
    #pragma unroll
    for (int j = 0; j < 64; ++j) {
      if (j >= W) continue;
      s[j + W] = s[j] * s0[11 - b];
      s[j]     = s[j] * c0[11 - b];
    }
  }

  // ---- layers 1-3 in tan form; state stays unscaled ----
  const float C1 = layer_t<1>(s, a, thetas, lane, lane4);
  const float C2 = layer_t<2>(s, a, thetas, lane, lane4);
  const float C3 = layer_t<3>(s, a, thetas, lane, lane4);
  const float Ct  = C1 * C2 * C3;
  const float Csq = Ct * Ct;

  // probabilities (unscaled)
  #pragma unroll
  for (int j = 0; j < 64; ++j) s[j] *= s[j];

  // in-register Walsh-Hadamard over the 6 register bits:
  // s[m] <- sum_j (-1)^popc(j&m) p[j]
  #pragma unroll
  for (int b = 0; b < 6; ++b) {
    const int W = 1 << b;
    #pragma unroll
    for (int j0 = 0; j0 < 64; ++j0) {
      if (j0 & W) continue;
      const int j1 = j0 | W;
      const float u = s[j0], v = s[j1];
      s[j0] = u + v;
      s[j1] = u - v;
    }
  }

  epi_rec<0>(s, Csq, lane, lane4, out, w);
}

extern "C" void kernel_launch(void* const* d_in, const int* in_sizes, int n_in,
                              void* d_out, int out_size, void* d_ws, size_t ws_size,
                              hipStream_t stream) {
  const float* ang    = (const float*)d_in[0];
  const float* thetas = (const float*)d_in[1];
  float* out          = (float*)d_out;
  const int B = in_sizes[0] / NQ;
  const int threads = 256;
  const int blocks = (B * 64 + threads - 1) / threads;
  hipLaunchKernelGGL(vqc_kernel, dim3(blocks), dim3(threads), 0, stream,
                     ang, thetas, out, B);
}

// Round 8
// 69.135 us; speedup vs baseline: 3.7400x; 1.0358x over previous
//
#include <hip/hip_runtime.h>

#define NQ 12
#define NL 4

typedef float f32x2 __attribute__((ext_vector_type(2)));

// ---------------------------------------------------------------------------
// Compile-time CNOT tracking as a GF(2) linear map (rounds 1-5, verified).
// RY(l,q) in tan form: mine'[i] = mine[i] + T(i)*mine[i^mk],
//   T(i) = +t iff parity(rm & i) odd else -t  (t = tan(angle/2); cos factors
//   accumulate into Ctot, folded into outputs as Ctot^2).
// State: f32x2 s2[32]; global index i = (lane<<6) | (2r+h).
// ROUND 8: verified mechanisms ONLY — builtin update_dpp, ds_swizzle,
// ds_bpermute. NO raw permlane asm (suspected VGPR-hazard bug in r6/r7).
// Packing via __builtin_elementwise_fma on f32x2 (compiler emits
// v_pk_fma_f32 and handles all hazards).
// ---------------------------------------------------------------------------
struct MaskTab { int mk[NL][NQ]; int rm[NL][NQ]; int rout[NQ]; };

static constexpr MaskTab build_masks() {
  MaskTab T{};
  unsigned col[NQ] = {};
  unsigned inv[NQ] = {};
  for (int k = 0; k < NQ; ++k) { col[k] = 1u << k; inv[k] = 1u << k; }
  for (int l = 0; l < NL; ++l) {
    for (int q = 0; q < NQ; ++q) {
      const int p = NQ - 1 - q;
      T.mk[l][q] = (int)inv[p];
      int rm = 0;
      for (int k = 0; k < NQ; ++k) rm |= (int)(((col[k] >> p) & 1u) << k);
      T.rm[l][q] = rm;
    }
    for (int q = 0; q < NQ - 1; ++q) {
      const int pc = NQ - 1 - q, pt = NQ - 2 - q;
      for (int k = 0; k < NQ; ++k) col[k] ^= ((col[k] >> pc) & 1u) << pt;
      inv[pc] ^= inv[pt];
    }
  }
  for (int q = 0; q < NQ; ++q) {
    const int p = NQ - 1 - q;
    int rm = 0;
    for (int k = 0; k < NQ; ++k) rm |= (int)(((col[k] >> p) & 1u) << k);
    T.rout[q] = rm;
  }
  return T;
}
static constexpr MaskTab MT = build_masks();

// ---------------- compile-time utils ----------------
constexpr int cpar(int j, int m) { return __builtin_popcount((unsigned)(j & m)) & 1; }
constexpr int chb(int m) { return m ? (1 << (31 - __builtin_clz((unsigned)m))) : 0; }
constexpr bool dpp_ok(int d) { return d==1||d==2||d==3||d==7||d==8||d==15; }
constexpr int dpp_ctrl_for(int d) {
  return d==1?0xB1 : d==2?0x4E : d==3?0x1B : d==7?0x141 : d==8?0x128 : 0x140;
}

template <int V> struct ic_ { static constexpr int v = V; };
template <int I, int N, typename F>
__device__ __forceinline__ void sfor(F&& f) {
  if constexpr (I < N) { f(ic_<I>{}); sfor<I + 1, N>(f); }
}

// ---------------- cross-lane primitives (all verified in passing rounds) ----
template <int CTRL>
__device__ __forceinline__ float dppf(float x) {
  return __int_as_float(__builtin_amdgcn_update_dpp(0, __float_as_int(x), CTRL, 0xF, 0xF, false));
}
template <int PAT>
__device__ __forceinline__ float swzf(float x) {
  return __int_as_float(__builtin_amdgcn_ds_swizzle(__float_as_int(x), PAT));
}
__device__ __forceinline__ float bpermf(int idx_bytes, float x) {
  return __int_as_float(__builtin_amdgcn_ds_bpermute(idx_bytes, __float_as_int(x)));
}

// packed helpers (pure compiler codegen)
__device__ __forceinline__ f32x2 swap_halves(f32x2 v) {
  return __builtin_shufflevector(v, v, 1, 0);
}
template <int S0, int S1>
__device__ __forceinline__ f32x2 tsel(float tp, float tn) {
  f32x2 r; r.x = S0 ? tn : tp; r.y = S1 ? tn : tp; return r;
}
__device__ __forceinline__ f32x2 pfma(f32x2 t, f32x2 p, f32x2 s) {
  return __builtin_elementwise_fma(t, p, s);
}

// lane-parity base sign: odd parity -> +t, even -> -t (rounds 2-5 verified)
template <int MASK>
__device__ __forceinline__ float lane_sign(float t, int lane) {
  if constexpr (MASK == 0) return -t;
  else return (__popc(lane & MASK) & 1) ? t : -t;
}

// ---------------- one RY gate (tan form) ----------------
template <int L, int Q>
__device__ __forceinline__ void gate(f32x2 (&s2)[32], float t, int lane) {
  constexpr int MK  = MT.mk[L][Q];
  constexpr int RM  = MT.rm[L][Q];
  constexpr int MKL = (MK >> 6) & 63;
  constexpr int MKO = MK & 63;
  constexpr int RMH = (RM >> 6) & 63;
  constexpr int RMO = RM & 63;
  const float tl  = lane_sign<RMH>(t, lane);
  const float tln = -tl;

  if constexpr (MKL == 0) {
    // ---- register-space butterfly (packed) ----
    if constexpr (MKO == 1) {
      sfor<0, 32>([&](auto RC) {
        constexpr int r = decltype(RC)::v;
        const f32x2 A = s2[r];
        s2[r] = pfma(tsel<cpar(2*r,RMO), cpar(2*r+1,RMO)>(tl,tln), swap_halves(A), A);
      });
    } else if constexpr ((MKO & 1) == 0) {
      constexpr int M2 = MKO >> 1;
      constexpr int HB = chb(M2);
      sfor<0, 32>([&](auto RC) {
        constexpr int r0 = decltype(RC)::v;
        if constexpr ((r0 & HB) == 0) {
          constexpr int r1 = r0 ^ M2;
          const f32x2 A = s2[r0], B = s2[r1];
          s2[r0] = pfma(tsel<cpar(2*r0,RMO), cpar(2*r0+1,RMO)>(tl,tln), B, A);
          s2[r1] = pfma(tsel<cpar(2*r1,RMO), cpar(2*r1+1,RMO)>(tl,tln), A, B);
        }
      });
    } else {
      // odd mask > 1: partner is the half-swapped other register
      constexpr int M2 = MKO >> 1;
      constexpr int HB = chb(M2);
      sfor<0, 32>([&](auto RC) {
        constexpr int r0 = decltype(RC)::v;
        if constexpr ((r0 & HB) == 0) {
          constexpr int r1 = r0 ^ M2;
          const f32x2 A = s2[r0], B = s2[r1];
          s2[r0] = pfma(tsel<cpar(2*r0,RMO), cpar(2*r0+1,RMO)>(tl,tln), swap_halves(B), A);
          s2[r1] = pfma(tsel<cpar(2*r1,RMO), cpar(2*r1+1,RMO)>(tl,tln), swap_halves(A), B);
        }
      });
    }
  } else if constexpr (dpp_ok(MKL) && MKO == 0) {
    // ---- pure cross-lane DPP gate (builtin fetch + packed fma) ----
    constexpr int CT = dpp_ctrl_for(MKL);
    sfor<0, 32>([&](auto RC) {
      constexpr int r = decltype(RC)::v;
      f32x2 p; p.x = dppf<CT>(s2[r].x); p.y = dppf<CT>(s2[r].y);
      s2[r] = pfma(tsel<cpar(2*r,RMO), cpar(2*r+1,RMO)>(tl,tln), p, s2[r]);
    });
  } else if constexpr (dpp_ok(MKL)) {
    // ---- mixed: DPP lane fetch + packed register butterfly (MKO even) ----
    constexpr int CT = dpp_ctrl_for(MKL);
    constexpr int M2 = MKO >> 1;
    constexpr int HB = chb(M2);
    sfor<0, 32>([&](auto RC) {
      constexpr int r0 = decltype(RC)::v;
      if constexpr ((r0 & HB) == 0) {
        constexpr int r1 = r0 ^ M2;
        f32x2 p, pq;
        p.x  = dppf<CT>(s2[r1].x); p.y  = dppf<CT>(s2[r1].y);
        pq.x = dppf<CT>(s2[r0].x); pq.y = dppf<CT>(s2[r0].y);
        s2[r0] = pfma(tsel<cpar(2*r0,RMO), cpar(2*r0+1,RMO)>(tl,tln), p,  s2[r0]);
        s2[r1] = pfma(tsel<cpar(2*r1,RMO), cpar(2*r1+1,RMO)>(tl,tln), pq, s2[r1]);
      }
    });
  } else if constexpr (MKL <= 31) {
    // ---- DS swizzle gate (MKO==0 for all such masks) ----
    constexpr int PAT = (MKL << 10) | 0x1F;
    sfor<0, 32>([&](auto RC) {
      constexpr int r = decltype(RC)::v;
      f32x2 p; p.x = swzf<PAT>(s2[r].x); p.y = swzf<PAT>(s2[r].y);
      s2[r] = pfma(tsel<cpar(2*r,RMO), cpar(2*r+1,RMO)>(tl,tln), p, s2[r]);
    });
  } else {
    // ---- DS bpermute gate (MKL in {48, 40, 60}; MKO==0) ----
    const int idx = (lane ^ MKL) << 2;
    sfor<0, 32>([&](auto RC) {
      constexpr int r = decltype(RC)::v;
      f32x2 p; p.x = bpermf(idx, s2[r].x); p.y = bpermf(idx, s2[r].y);
      s2[r] = pfma(tsel<cpar(2*r,RMO), cpar(2*r+1,RMO)>(tl,tln), p, s2[r]);
    });
  }
}

template <int L, int Q>
__device__ __forceinline__ void round_rec(f32x2 (&s2)[32], const float (&t)[NQ], int lane) {
  if constexpr (Q < NQ) {
    gate<L, Q>(s2, t[Q], lane);
    round_rec<L, Q + 1>(s2, t, lane);
  }
}

template <int L>
__device__ __forceinline__ float layer_t(f32x2 (&s2)[32], const float (&a)[NQ],
                                         const float* __restrict__ thetas, int lane) {
  const float4 T0 = *(const float4*)(thetas + L * NQ);
  const float4 T1 = *(const float4*)(thetas + L * NQ + 4);
  const float4 T2v = *(const float4*)(thetas + L * NQ + 8);
  const float th[NQ] = {T0.x, T0.y, T0.z, T0.w, T1.x, T1.y, T1.z, T1.w,
                        T2v.x, T2v.y, T2v.z, T2v.w};
  float t[NQ];
  float C = 1.0f;
  #pragma unroll
  for (int q = 0; q < NQ; ++q) {
    float sn, cs;
    __sincosf(0.5f * (a[q] + th[q]), &sn, &cs);
    t[q] = __fdividef(sn, cs);
    C *= cs;
  }
  round_rec<L, 0>(s2, t, lane);
  return C;
}

__global__ __launch_bounds__(256, 2) void vqc_kernel(const float* __restrict__ ang,
                                                     const float* __restrict__ thetas,
                                                     float* __restrict__ out, int B) {
  const int tid  = blockIdx.x * blockDim.x + threadIdx.x;
  const int w    = tid >> 6;
  const int lane = tid & 63;
  if (w >= B) return;

  const float4 A0 = *(const float4*)(ang + w * NQ);
  const float4 A1 = *(const float4*)(ang + w * NQ + 4);
  const float4 A2 = *(const float4*)(ang + w * NQ + 8);
  const float a[NQ] = {A0.x, A0.y, A0.z, A0.w, A1.x, A1.y, A1.z, A1.w,
                       A2.x, A2.y, A2.z, A2.w};

  // ---- layer 0 on |0..0>: product state built directly (round-4/5 verified) ----
  float c0[NQ], s0[NQ];
  #pragma unroll
  for (int q = 0; q < NQ; ++q) {
    __sincosf(0.5f * (a[q] + thetas[q]), &s0[q], &c0[q]);
  }
  float flane = 1.0f;
  #pragma unroll
  for (int k = 0; k < 6; ++k) {
    flane *= ((lane >> k) & 1) ? s0[5 - k] : c0[5 - k];
  }
  // base over index bits 1..5 (qubits 10..6), then packed tensor with qubit 11
  float base[32];
  base[0] = flane;
  #pragma unroll
  for (int k = 0; k < 5; ++k) {
    const int W = 1 << k;
    #pragma unroll
    for (int j = 0; j < 32; ++j) {
      if (j >= W) continue;
      base[j + W] = base[j] * s0[10 - k];
      base[j]     = base[j] * c0[10 - k];
    }
  }
  f32x2 q11; q11.x = c0[11]; q11.y = s0[11];
  f32x2 s2[32];
  #pragma unroll
  for (int r = 0; r < 32; ++r) s2[r] = base[r] * q11;

  // ---- layers 1-3 (tan form) ----
  const float C1 = layer_t<1>(s2, a, thetas, lane);
  const float C2 = layer_t<2>(s2, a, thetas, lane);
  const float C3 = layer_t<3>(s2, a, thetas, lane);
  const float Ct  = C1 * C2 * C3;
  const float Csq = Ct * Ct;

  // probabilities (unscaled, packed)
  #pragma unroll
  for (int r = 0; r < 32; ++r) s2[r] = s2[r] * s2[r];

  // Walsh-Hadamard over the 6 register bits:
  // stage 0 (index bit 0, intra-register)
  #pragma unroll
  for (int r = 0; r < 32; ++r) {
    const float u = s2[r].x, v = s2[r].y;
    s2[r].x = u + v;
    s2[r].y = u - v;
  }
  // stages 1-5 (register-index bits, packed)
  #pragma unroll
  for (int b = 0; b < 5; ++b) {
    const int W = 1 << b;
    #pragma unroll
    for (int r0 = 0; r0 < 32; ++r0) {
      if (r0 & W) continue;
      const int r1 = r0 | W;
      const f32x2 u = s2[r0], v = s2[r1];
      s2[r0] = u + v;
      s2[r1] = u - v;
    }
  }

  // ---- epilogue: 12 signed full-wave reductions ----
  sfor<0, NQ>([&](auto QC) {
    constexpr int q   = decltype(QC)::v;
    constexpr int RM  = MT.rout[q];
    constexpr int RMH = (RM >> 6) & 63;
    constexpr int RMO = RM & 63;
    float v = (RMO & 1) ? s2[RMO >> 1].y : s2[RMO >> 1].x;
    if constexpr (RMH != 0) {
      const int sx = (__popc(lane & RMH) & 1) << 31;  // odd lane parity -> minus
      v = __int_as_float(__float_as_int(v) ^ sx);
    }
    v += dppf<0xB1>(v);               // xor1
    v += dppf<0x4E>(v);               // xor2
    v += swzf<(4 << 10) | 0x1F>(v);   // xor4
    v += dppf<0x128>(v);              // xor8
    v += swzf<(16 << 10) | 0x1F>(v);  // xor16
    v += bpermf((lane ^ 32) << 2, v); // xor32
    if (lane == 0) out[w * NQ + q] = v * Csq;
  });
}

extern "C" void kernel_launch(void* const* d_in, const int* in_sizes, int n_in,
                              void* d_out, int out_size, void* d_ws, size_t ws_size,
                              hipStream_t stream) {
  const float* ang    = (const float*)d_in[0];
  const float* thetas = (const float*)d_in[1];
  float* out          = (float*)d_out;
  const int B = in_sizes[0] / NQ;
  const int threads = 256;
  const int blocks = (B * 64 + threads - 1) / threads;
  hipLaunchKernelGGL(vqc_kernel, dim3(blocks), dim3(threads), 0, stream,
                     ang, thetas, out, B);
}

// Round 9
// 66.815 us; speedup vs baseline: 3.8699x; 1.0347x over previous
//
#include <hip/hip_runtime.h>

#define NQ 12
#define NL 4

typedef float f32x2 __attribute__((ext_vector_type(2)));

// ---------------------------------------------------------------------------
// Compile-time CNOT tracking as a GF(2) linear map (rounds 1-8, verified).
// RY(l,q) in tan form: mine'[i] = mine[i] + T(i)*mine[i^mk],
//   T(i) = +t iff parity(rm & i) odd else -t; cos factors -> Ctot^2 at end.
// ROUND 9 LAYOUT: TWO batch elements per wave.
//   physical lane = (elem << 5) | l5;  global index i = (l5 << 7) | (r<<1) | h
//   -> index bits 0-6 = register dims (64 x f32x2), bits 7-11 = lane dims.
// All cross-lane masks are now <= 31: ds_swizzle bit-mode (within 32-lane
// groups, never crosses the element boundary) or DPP / 2-DPP compositions.
// No ds_bpermute anywhere.
// ---------------------------------------------------------------------------
struct MaskTab { int mk[NL][NQ]; int rm[NL][NQ]; int rout[NQ]; };

static constexpr MaskTab build_masks() {
  MaskTab T{};
  unsigned col[NQ] = {};
  unsigned inv[NQ] = {};
  for (int k = 0; k < NQ; ++k) { col[k] = 1u << k; inv[k] = 1u << k; }
  for (int l = 0; l < NL; ++l) {
    for (int q = 0; q < NQ; ++q) {
      const int p = NQ - 1 - q;
      T.mk[l][q] = (int)inv[p];
      int rm = 0;
      for (int k = 0; k < NQ; ++k) rm |= (int)(((col[k] >> p) & 1u) << k);
      T.rm[l][q] = rm;
    }
    for (int q = 0; q < NQ - 1; ++q) {
      const int pc = NQ - 1 - q, pt = NQ - 2 - q;
      for (int k = 0; k < NQ; ++k) col[k] ^= ((col[k] >> pc) & 1u) << pt;
      inv[pc] ^= inv[pt];
    }
  }
  for (int q = 0; q < NQ; ++q) {
    const int p = NQ - 1 - q;
    int rm = 0;
    for (int k = 0; k < NQ; ++k) rm |= (int)(((col[k] >> p) & 1u) << k);
    T.rout[q] = rm;
  }
  return T;
}
static constexpr MaskTab MT = build_masks();

// ---------------- compile-time utils ----------------
constexpr int cpar(int j, int m) { return __builtin_popcount((unsigned)(j & m)) & 1; }
constexpr int chb(int m) { return m ? (1 << (31 - __builtin_clz((unsigned)m))) : 0; }
constexpr bool dpp_ok(int d) { return d==1||d==2||d==3||d==7||d==8||d==15; }
constexpr int dpp_ctrl_for(int d) {
  return d==1?0xB1 : d==2?0x4E : d==3?0x1B : d==7?0x141 : d==8?0x128 : 0x140;
}
// 2-DPP compositions of verified ctrls: 5=7^2, 6=7^1, 10=8^2, 12=15^3
constexpr bool synth2_ok(int d) { return d==5||d==6||d==10||d==12; }
constexpr int synth_a(int d) { return d==5?0x141 : d==6?0x141 : d==10?0x128 : 0x140; }
constexpr int synth_b(int d) { return d==5?0x4E  : d==6?0xB1  : d==10?0x4E  : 0x1B; }

template <int V> struct ic_ { static constexpr int v = V; };
template <int I, int N, typename F>
__device__ __forceinline__ void sfor(F&& f) {
  if constexpr (I < N) { f(ic_<I>{}); sfor<I + 1, N>(f); }
}

// ---------------- cross-lane primitives (verified in passing rounds) -------
template <int CTRL>
__device__ __forceinline__ float dppf(float x) {
  return __int_as_float(__builtin_amdgcn_update_dpp(0, __float_as_int(x), CTRL, 0xF, 0xF, false));
}
template <int PAT>
__device__ __forceinline__ float swzf(float x) {
  return __int_as_float(__builtin_amdgcn_ds_swizzle(__float_as_int(x), PAT));
}

// packed helpers (pure compiler codegen)
__device__ __forceinline__ f32x2 swap_halves(f32x2 v) {
  return __builtin_shufflevector(v, v, 1, 0);
}
template <int S0, int S1>
__device__ __forceinline__ f32x2 tsel(float tp, float tn) {
  f32x2 r; r.x = S0 ? tn : tp; r.y = S1 ? tn : tp; return r;
}
__device__ __forceinline__ f32x2 pfma(f32x2 t, f32x2 p, f32x2 s) {
  return __builtin_elementwise_fma(t, p, s);
}

// lane-parity base sign: odd parity -> +t, even -> -t (rounds 2-8 verified).
// MASK is within bits 0-4, so the element bit (lane bit 5) never contributes.
template <int MASK>
__device__ __forceinline__ float lane_sign(float t, int lane) {
  if constexpr (MASK == 0) return -t;
  else return (__popc(lane & MASK) & 1) ? t : -t;
}

// ---------------- one RY gate (tan form), 2-elem layout ----------------
template <int L, int Q>
__device__ __forceinline__ void gate(f32x2 (&s2)[64], float t, int lane) {
  constexpr int MK  = MT.mk[L][Q];
  constexpr int RM  = MT.rm[L][Q];
  constexpr int MKL = (MK >> 7) & 31;   // lane-xor (physical lane bits 0-4)
  constexpr int MKO = MK & 127;         // register+half xor (index bits 0-6)
  constexpr int RMH = (RM >> 7) & 31;
  constexpr int RMO = RM & 127;
  const float tl  = lane_sign<RMH>(t, lane);
  const float tln = -tl;

  // partner lane-fetch: identity / single DPP / 2-DPP composition / swizzle
  auto FETCH1 = [&](float x) -> float {
    if constexpr (MKL == 0) return x;
    else if constexpr (dpp_ok(MKL)) return dppf<dpp_ctrl_for(MKL)>(x);
    else if constexpr (synth2_ok(MKL)) return dppf<synth_b(MKL)>(dppf<synth_a(MKL)>(x));
    else return swzf<(MKL << 10) | 0x1F>(x);
  };
  auto PF = [&](f32x2 v) -> f32x2 {
    if constexpr (MKL == 0) return v;
    else { f32x2 p; p.x = FETCH1(v.x); p.y = FETCH1(v.y); return p; }
  };

  constexpr int M2 = MKO >> 1;   // f32x2-register xor
  constexpr int HS = MKO & 1;    // half swap (index bit 0)
  if constexpr (M2 == 0) {
    sfor<0, 64>([&](auto RC) {
      constexpr int r = decltype(RC)::v;
      f32x2 p = PF(s2[r]);
      if constexpr (HS) p = swap_halves(p);
      s2[r] = pfma(tsel<cpar(2*r, RMO), cpar(2*r+1, RMO)>(tl, tln), p, s2[r]);
    });
  } else {
    constexpr int HB = chb(M2);
    sfor<0, 64>([&](auto RC) {
      constexpr int r0 = decltype(RC)::v;
      if constexpr ((r0 & HB) == 0) {
        constexpr int r1 = r0 ^ M2;
        f32x2 pa = PF(s2[r1]);
        f32x2 pb = PF(s2[r0]);
        if constexpr (HS) { pa = swap_halves(pa); pb = swap_halves(pb); }
        s2[r0] = pfma(tsel<cpar(2*r0, RMO), cpar(2*r0+1, RMO)>(tl, tln), pa, s2[r0]);
        s2[r1] = pfma(tsel<cpar(2*r1, RMO), cpar(2*r1+1, RMO)>(tl, tln), pb, s2[r1]);
      }
    });
  }
}

template <int L, int Q>
__device__ __forceinline__ void round_rec(f32x2 (&s2)[64], const float (&t)[NQ], int lane) {
  if constexpr (Q < NQ) {
    gate<L, Q>(s2, t[Q], lane);
    round_rec<L, Q + 1>(s2, t, lane);
  }
}

template <int L>
__device__ __forceinline__ float layer_t(f32x2 (&s2)[64], const float (&a)[NQ],
                                         const float* __restrict__ thetas, int lane) {
  const float4 T0 = *(const float4*)(thetas + L * NQ);
  const float4 T1 = *(const float4*)(thetas + L * NQ + 4);
  const float4 T2v = *(const float4*)(thetas + L * NQ + 8);
  const float th[NQ] = {T0.x, T0.y, T0.z, T0.w, T1.x, T1.y, T1.z, T1.w,
                        T2v.x, T2v.y, T2v.z, T2v.w};
  float t[NQ];
  float C = 1.0f;
  #pragma unroll
  for (int q = 0; q < NQ; ++q) {
    float sn, cs;
    __sincosf(0.5f * (a[q] + th[q]), &sn, &cs);
    t[q] = __fdividef(sn, cs);
    C *= cs;
  }
  round_rec<L, 0>(s2, t, lane);
  return C;
}

__global__ __launch_bounds__(256, 2) void vqc_kernel(const float* __restrict__ ang,
                                                     const float* __restrict__ thetas,
                                                     float* __restrict__ out, int B) {
  const int tid  = blockIdx.x * blockDim.x + threadIdx.x;
  const int gw   = tid >> 6;          // wave index: handles elements 2gw, 2gw+1
  const int lane = tid & 63;
  if (2 * gw >= B) return;
  const int l5   = lane & 31;
  int row = 2 * gw + (lane >> 5);     // this lane's batch element
  const int row_store = row;
  if (row >= B) row = B - 1;          // clamp loads (odd-B safety)

  const float4 A0 = *(const float4*)(ang + row * NQ);
  const float4 A1 = *(const float4*)(ang + row * NQ + 4);
  const float4 A2 = *(const float4*)(ang + row * NQ + 8);
  const float a[NQ] = {A0.x, A0.y, A0.z, A0.w, A1.x, A1.y, A1.z, A1.w,
                       A2.x, A2.y, A2.z, A2.w};

  // ---- layer 0 on |0..0>: per-element product state ----
  // index bit b -> qubit 11-b.  lane bits: i bit 7+k = l5 bit k -> qubit 4-k.
  // register bits: r bit k = i bit k+1 -> qubit 10-k.  half bit -> qubit 11.
  float c0[NQ], s0[NQ];
  #pragma unroll
  for (int q = 0; q < NQ; ++q) {
    __sincosf(0.5f * (a[q] + thetas[q]), &s0[q], &c0[q]);
  }
  float flane = 1.0f;
  #pragma unroll
  for (int k = 0; k < 5; ++k) {
    flane *= ((l5 >> k) & 1) ? s0[4 - k] : c0[4 - k];
  }
  f32x2 s2[64];
  { f32x2 h0; h0.x = c0[11] * flane; h0.y = s0[11] * flane; s2[0] = h0; }
  #pragma unroll
  for (int k = 0; k < 6; ++k) {
    const int W = 1 << k;
    #pragma unroll
    for (int j = 0; j < 64; ++j) {
      if (j >= W) continue;
      s2[j + W] = s2[j] * s0[10 - k];
      s2[j]     = s2[j] * c0[10 - k];
    }
  }

  // ---- layers 1-3 (tan form) ----
  const float C1 = layer_t<1>(s2, a, thetas, lane);
  const float C2 = layer_t<2>(s2, a, thetas, lane);
  const float C3 = layer_t<3>(s2, a, thetas, lane);
  const float Ct  = C1 * C2 * C3;
  const float Csq = Ct * Ct;

  // probabilities (unscaled, packed)
  #pragma unroll
  for (int r = 0; r < 64; ++r) s2[r] = s2[r] * s2[r];

  // Walsh-Hadamard over the 7 register-dim bits:
  // stage 0: intra-f32x2 (index bit 0)
  #pragma unroll
  for (int r = 0; r < 64; ++r) {
    const float u = s2[r].x, v = s2[r].y;
    s2[r].x = u + v;
    s2[r].y = u - v;
  }
  // stages 1-6: register bits 0..5
  #pragma unroll
  for (int b = 0; b < 6; ++b) {
    const int W = 1 << b;
    #pragma unroll
    for (int r0 = 0; r0 < 64; ++r0) {
      if (r0 & W) continue;
      const int r1 = r0 | W;
      const f32x2 u = s2[r0], v = s2[r1];
      s2[r0] = u + v;
      s2[r1] = u - v;
    }
  }

  // ---- epilogue: 12 signed reductions over lane bits 0-4 (per element) ----
  sfor<0, NQ>([&](auto QC) {
    constexpr int q   = decltype(QC)::v;
    constexpr int RM  = MT.rout[q];
    constexpr int RMH = (RM >> 7) & 31;
    constexpr int RMO = RM & 127;
    float v = (RMO & 1) ? s2[RMO >> 1].y : s2[RMO >> 1].x;
    if constexpr (RMH != 0) {
      const int sx = (__popc(lane & RMH) & 1) << 31;  // odd lane parity -> minus
      v = __int_as_float(__float_as_int(v) ^ sx);
    }
    v += dppf<0xB1>(v);               // xor1
    v += dppf<0x4E>(v);               // xor2
    v += swzf<(4 << 10) | 0x1F>(v);   // xor4
    v += dppf<0x128>(v);              // xor8
    v += swzf<(16 << 10) | 0x1F>(v);  // xor16 (within 32-lane group)
    if ((lane & 31) == 0 && row_store < B) out[row_store * NQ + q] = v * Csq;
  });
}

extern "C" void kernel_launch(void* const* d_in, const int* in_sizes, int n_in,
                              void* d_out, int out_size, void* d_ws, size_t ws_size,
                              hipStream_t stream) {
  const float* ang    = (const float*)d_in[0];
  const float* thetas = (const float*)d_in[1];
  float* out          = (float*)d_out;
  const int B = in_sizes[0] / NQ;
  const int waves = (B + 1) / 2;       // 2 elements per wave
  const int threads = 256;
  const int blocks = (waves * 64 + threads - 1) / threads;
  hipLaunchKernelGGL(vqc_kernel, dim3(blocks), dim3(threads), 0, stream,
                     ang, thetas, out, B);
}

// Round 10
// 57.715 us; speedup vs baseline: 4.4801x; 1.1577x over previous
//
#include <hip/hip_runtime.h>

#define NQ 12
#define NL 4

typedef float f32x2 __attribute__((ext_vector_type(2)));

// ---------------------------------------------------------------------------
// Compile-time CNOT tracking as a GF(2) linear map (rounds 1-9, verified).
// RY(l,q) in tan form: mine'[i] = mine[i] + T(i)*mine[i^mk],
//   T(i) = +t iff parity(rm & i) odd else -t; cos factors -> Ctot^2 at end.
// LAYOUT (round 9, verified): TWO batch elements per wave.
//   physical lane = (elem << 5) | l5;  global index i = (l5 << 7) | (r<<1) | h
//   -> index bits 0-6 = register dims (64 x f32x2), bits 7-11 = lane dims.
// ROUND 10: (1) angle prep (48 sincos+div per thread, uniform per 32-lane
// group) replaced by distributed compute -> LDS slab -> vector read-back;
// (2) synth2 gates w/ masks 10,5 moved to idle DS pipe; (3) +/-t packed
// vectors hoisted per gate (constexpr-indexed).
// ---------------------------------------------------------------------------
struct MaskTab { int mk[NL][NQ]; int rm[NL][NQ]; int rout[NQ]; };

static constexpr MaskTab build_masks() {
  MaskTab T{};
  unsigned col[NQ] = {};
  unsigned inv[NQ] = {};
  for (int k = 0; k < NQ; ++k) { col[k] = 1u << k; inv[k] = 1u << k; }
  for (int l = 0; l < NL; ++l) {
    for (int q = 0; q < NQ; ++q) {
      const int p = NQ - 1 - q;
      T.mk[l][q] = (int)inv[p];
      int rm = 0;
      for (int k = 0; k < NQ; ++k) rm |= (int)(((col[k] >> p) & 1u) << k);
      T.rm[l][q] = rm;
    }
    for (int q = 0; q < NQ - 1; ++q) {
      const int pc = NQ - 1 - q, pt = NQ - 2 - q;
      for (int k = 0; k < NQ; ++k) col[k] ^= ((col[k] >> pc) & 1u) << pt;
      inv[pc] ^= inv[pt];
    }
  }
  for (int q = 0; q < NQ; ++q) {
    const int p = NQ - 1 - q;
    int rm = 0;
    for (int k = 0; k < NQ; ++k) rm |= (int)(((col[k] >> p) & 1u) << k);
    T.rout[q] = rm;
  }
  return T;
}
static constexpr MaskTab MT = build_masks();

// ---------------- compile-time utils ----------------
constexpr int cpar(int j, int m) { return __builtin_popcount((unsigned)(j & m)) & 1; }
constexpr int chb(int m) { return m ? (1 << (31 - __builtin_clz((unsigned)m))) : 0; }
constexpr bool dpp_ok(int d) { return d==1||d==2||d==3||d==7||d==8||d==15; }
constexpr int dpp_ctrl_for(int d) {
  return d==1?0xB1 : d==2?0x4E : d==3?0x1B : d==7?0x141 : d==8?0x128 : 0x140;
}
// 2-DPP compositions kept on VALU: 6=7^1, 12=15^3 (others go to DS)
constexpr bool synth2_ok(int d) { return d==6||d==12; }
constexpr int synth_a(int d) { return d==6?0x141 : 0x140; }
constexpr int synth_b(int d) { return d==6?0xB1  : 0x1B; }

template <int V> struct ic_ { static constexpr int v = V; };
template <int I, int N, typename F>
__device__ __forceinline__ void sfor(F&& f) {
  if constexpr (I < N) { f(ic_<I>{}); sfor<I + 1, N>(f); }
}

// ---------------- cross-lane primitives (verified rounds 4-9) -------
template <int CTRL>
__device__ __forceinline__ float dppf(float x) {
  return __int_as_float(__builtin_amdgcn_update_dpp(0, __float_as_int(x), CTRL, 0xF, 0xF, false));
}
template <int PAT>
__device__ __forceinline__ float swzf(float x) {
  return __int_as_float(__builtin_amdgcn_ds_swizzle(__float_as_int(x), PAT));
}

// packed helpers (pure compiler codegen)
__device__ __forceinline__ f32x2 swap_halves(f32x2 v) {
  return __builtin_shufflevector(v, v, 1, 0);
}
__device__ __forceinline__ f32x2 pfma(f32x2 t, f32x2 p, f32x2 s) {
  return __builtin_elementwise_fma(t, p, s);
}

// lane-parity base sign: odd parity -> +t, even -> -t (rounds 2-9 verified).
template <int MASK>
__device__ __forceinline__ float lane_sign(float t, int lane) {
  if constexpr (MASK == 0) return -t;
  else return (__popc(lane & MASK) & 1) ? t : -t;
}

// ---------------- one RY gate (tan form), 2-elem layout ----------------
template <int L, int Q>
__device__ __forceinline__ void gate(f32x2 (&s2)[64], float t, int lane) {
  constexpr int MK  = MT.mk[L][Q];
  constexpr int RM  = MT.rm[L][Q];
  constexpr int MKL = (MK >> 7) & 31;   // lane-xor (physical lane bits 0-4)
  constexpr int MKO = MK & 127;         // register+half xor (index bits 0-6)
  constexpr int RMH = (RM >> 7) & 31;
  constexpr int RMO = RM & 127;
  const float tl  = lane_sign<RMH>(t, lane);
  const float tln = -tl;
  // hoisted packed sign vectors, constexpr-indexed (no per-reg construction)
  f32x2 tvv[4];
  tvv[0].x = tl;  tvv[0].y = tl;
  tvv[1].x = tl;  tvv[1].y = tln;
  tvv[2].x = tln; tvv[2].y = tl;
  tvv[3].x = tln; tvv[3].y = tln;

  // partner lane-fetch: identity / single DPP / 2-DPP composition / swizzle
  auto FETCH1 = [&](float x) -> float {
    if constexpr (MKL == 0) return x;
    else if constexpr (dpp_ok(MKL)) return dppf<dpp_ctrl_for(MKL)>(x);
    else if constexpr (synth2_ok(MKL)) return dppf<synth_b(MKL)>(dppf<synth_a(MKL)>(x));
    else return swzf<(MKL << 10) | 0x1F>(x);
  };
  auto PF = [&](f32x2 v) -> f32x2 {
    if constexpr (MKL == 0) return v;
    else { f32x2 p; p.x = FETCH1(v.x); p.y = FETCH1(v.y); return p; }
  };

  constexpr int M2 = MKO >> 1;   // f32x2-register xor
  constexpr int HS = MKO & 1;    // half swap (index bit 0)
  if constexpr (M2 == 0) {
    sfor<0, 64>([&](auto RC) {
      constexpr int r = decltype(RC)::v;
      f32x2 p = PF(s2[r]);
      if constexpr (HS) p = swap_halves(p);
      s2[r] = pfma(tvv[2*cpar(2*r, RMO) + cpar(2*r+1, RMO)], p, s2[r]);
    });
  } else {
    constexpr int HB = chb(M2);
    sfor<0, 64>([&](auto RC) {
      constexpr int r0 = decltype(RC)::v;
      if constexpr ((r0 & HB) == 0) {
        constexpr int r1 = r0 ^ M2;
        f32x2 pa = PF(s2[r1]);
        f32x2 pb = PF(s2[r0]);
        if constexpr (HS) { pa = swap_halves(pa); pb = swap_halves(pb); }
        s2[r0] = pfma(tvv[2*cpar(2*r0, RMO) + cpar(2*r0+1, RMO)], pa, s2[r0]);
        s2[r1] = pfma(tvv[2*cpar(2*r1, RMO) + cpar(2*r1+1, RMO)], pb, s2[r1]);
      }
    });
  }
}

template <int L, int Q>
__device__ __forceinline__ void round_rec(f32x2 (&s2)[64], const float (&t)[NQ], int lane) {
  if constexpr (Q < NQ) {
    gate<L, Q>(s2, t[Q], lane);
    round_rec<L, Q + 1>(s2, t, lane);
  }
}

__global__ __launch_bounds__(256, 2) void vqc_kernel(const float* __restrict__ ang,
                                                     const float* __restrict__ thetas,
                                                     float* __restrict__ out, int B) {
  const int tid  = blockIdx.x * blockDim.x + threadIdx.x;
  const int gw   = tid >> 6;          // wave index: elements 2gw, 2gw+1
  const int lane = tid & 63;
  const int l5   = lane & 31;
  const int elem = lane >> 5;
  const int row_store = 2 * gw + elem;
  const int row = (row_store < B) ? row_store : (B - 1);   // clamp, no early exit

  // ---- distributed angle prep -> per-wave LDS slab ----
  // slab layout per element (64 floats): [0..35] tan(l=1..3,q), [36..47] c0, [48..59] s0
  __shared__ float prep[4][2][64];
  const int wib = threadIdx.x >> 6;
  float* P = &prep[wib][elem][0];

  float csprod;
  {
    // task 1: tau = l5 (< 36: tan task, l = 1 + tau/12, q = tau%12)
    const int tau1 = l5;
    const int lq1 = (1 + tau1 / 12) * NQ + (tau1 % 12);
    float sn, cs;
    __sincosf(0.5f * (ang[row * NQ + (tau1 % 12)] + thetas[lq1]), &sn, &cs);
    P[tau1] = __fdividef(sn, cs);
    csprod = cs;
    // task 2 (lanes l5 < 16): tau = l5 + 32
    if (l5 < 16) {
      const int tau2 = l5 + 32;
      if (tau2 < 36) {          // tan task (l=3, q=8..11)
        const int q2 = tau2 % 12;
        float sn2, cs2;
        __sincosf(0.5f * (ang[row * NQ + q2] + thetas[3 * NQ + q2]), &sn2, &cs2);
        P[tau2] = __fdividef(sn2, cs2);
        csprod *= cs2;
      } else {                  // layer-0 pair (q = tau2 - 36)
        const int q2 = tau2 - 36;
        float sn2, cs2;
        __sincosf(0.5f * (ang[row * NQ + q2] + thetas[q2]), &sn2, &cs2);
        P[36 + q2] = cs2;
        P[48 + q2] = sn2;
      }
    }
    // multiplicative reduce of cos over the 32-lane group (verified patterns)
    csprod *= dppf<0xB1>(csprod);
    csprod *= dppf<0x4E>(csprod);
    csprod *= swzf<(4 << 10) | 0x1F>(csprod);
    csprod *= dppf<0x128>(csprod);
    csprod *= swzf<(16 << 10) | 0x1F>(csprod);
  }
  const float Csq = csprod * csprod;
  __syncthreads();

  // vector read-back (broadcast reads, conflict-free)
  float t1[NQ], t2[NQ], t3[NQ], c0[NQ], s0[NQ];
  {
    const float4* P4 = (const float4*)P;
#define LD4(arr, base, idx) { float4 v = P4[idx]; arr[base]=v.x; arr[base+1]=v.y; arr[base+2]=v.z; arr[base+3]=v.w; }
    LD4(t1, 0, 0) LD4(t1, 4, 1) LD4(t1, 8, 2)
    LD4(t2, 0, 3) LD4(t2, 4, 4) LD4(t2, 8, 5)
    LD4(t3, 0, 6) LD4(t3, 4, 7) LD4(t3, 8, 8)
    LD4(c0, 0, 9) LD4(c0, 4, 10) LD4(c0, 8, 11)
    LD4(s0, 0, 12) LD4(s0, 4, 13) LD4(s0, 8, 14)
#undef LD4
  }

  // ---- layer 0 on |0..0>: per-element product state (round 9 verified) ----
  // lane bits: i bit 7+k = l5 bit k -> qubit 4-k; reg bit k -> qubit 10-k;
  // half bit -> qubit 11.
  float flane = 1.0f;
  #pragma unroll
  for (int k = 0; k < 5; ++k) {
    flane *= ((l5 >> k) & 1) ? s0[4 - k] : c0[4 - k];
  }
  f32x2 s2[64];
  { f32x2 h0; h0.x = c0[11] * flane; h0.y = s0[11] * flane; s2[0] = h0; }
  #pragma unroll
  for (int k = 0; k < 6; ++k) {
    const int W = 1 << k;
    #pragma unroll
    for (int j = 0; j < 64; ++j) {
      if (j >= W) continue;
      s2[j + W] = s2[j] * s0[10 - k];
      s2[j]     = s2[j] * c0[10 - k];
    }
  }

  // ---- layers 1-3 (tan form) ----
  round_rec<1, 0>(s2, t1, lane);
  round_rec<2, 0>(s2, t2, lane);
  round_rec<3, 0>(s2, t3, lane);

  // probabilities (unscaled, packed)
  #pragma unroll
  for (int r = 0; r < 64; ++r) s2[r] = s2[r] * s2[r];

  // Walsh-Hadamard over the 7 register-dim bits
  #pragma unroll
  for (int r = 0; r < 64; ++r) {
    const float u = s2[r].x, v = s2[r].y;
    s2[r].x = u + v;
    s2[r].y = u - v;
  }
  #pragma unroll
  for (int b = 0; b < 6; ++b) {
    const int W = 1 << b;
    #pragma unroll
    for (int r0 = 0; r0 < 64; ++r0) {
      if (r0 & W) continue;
      const int r1 = r0 | W;
      const f32x2 u = s2[r0], v = s2[r1];
      s2[r0] = u + v;
      s2[r1] = u - v;
    }
  }

  // ---- epilogue: 12 signed reductions over lane bits 0-4 (per element) ----
  sfor<0, NQ>([&](auto QC) {
    constexpr int q   = decltype(QC)::v;
    constexpr int RM  = MT.rout[q];
    constexpr int RMH = (RM >> 7) & 31;
    constexpr int RMO = RM & 127;
    float v = (RMO & 1) ? s2[RMO >> 1].y : s2[RMO >> 1].x;
    if constexpr (RMH != 0) {
      const int sx = (__popc(lane & RMH) & 1) << 31;  // odd lane parity -> minus
      v = __int_as_float(__float_as_int(v) ^ sx);
    }
    v += dppf<0xB1>(v);               // xor1
    v += dppf<0x4E>(v);               // xor2
    v += swzf<(4 << 10) | 0x1F>(v);   // xor4
    v += dppf<0x128>(v);              // xor8
    v += swzf<(16 << 10) | 0x1F>(v);  // xor16 (within 32-lane group)
    if (l5 == 0 && row_store < B) out[row_store * NQ + q] = v * Csq;
  });
}

extern "C" void kernel_launch(void* const* d_in, const int* in_sizes, int n_in,
                              void* d_out, int out_size, void* d_ws, size_t ws_size,
                              hipStream_t stream) {
  const float* ang    = (const float*)d_in[0];
  const float* thetas = (const float*)d_in[1];
  float* out          = (float*)d_out;
  const int B = in_sizes[0] / NQ;
  const int waves = (B + 1) / 2;       // 2 elements per wave
  const int threads = 256;
  const int blocks = (waves * 64 + threads - 1) / threads;
  hipLaunchKernelGGL(vqc_kernel, dim3(blocks), dim3(threads), 0, stream,
                     ang, thetas, out, B);
}

// Round 11
// 57.446 us; speedup vs baseline: 4.5010x; 1.0047x over previous
//
#include <hip/hip_runtime.h>

#define NQ 12
#define NL 4

typedef float f32x2 __attribute__((ext_vector_type(2)));

// ---------------------------------------------------------------------------
// Compile-time CNOT tracking as a GF(2) linear map (rounds 1-10, verified).
// RY(l,q) in tan form: mine'[i] = mine[i] + T(i)*mine[i^mk],
//   T(i) = +t iff parity(rm & i) odd else -t; cos factors -> Ctot^2 at end.
// LAYOUT (rounds 9-10, verified): TWO batch elements per wave.
//   physical lane = (elem << 5) | l5;  global index i = (l5 << 7) | (r<<1) | h
// ROUND 11: codegen-shaped gate paths —
//   * half-swap register gates: scalar FMAs (no swap_halves movs)
//   * DPP/synth2 gates: scalar fmaf(dpp(x), t, x) tied-dst form (DPPCombine)
//   * non-HS register / swizzle gates: packed pfma, 2 hoisted sign vectors
// ---------------------------------------------------------------------------
struct MaskTab { int mk[NL][NQ]; int rm[NL][NQ]; int rout[NQ]; };

static constexpr MaskTab build_masks() {
  MaskTab T{};
  unsigned col[NQ] = {};
  unsigned inv[NQ] = {};
  for (int k = 0; k < NQ; ++k) { col[k] = 1u << k; inv[k] = 1u << k; }
  for (int l = 0; l < NL; ++l) {
    for (int q = 0; q < NQ; ++q) {
      const int p = NQ - 1 - q;
      T.mk[l][q] = (int)inv[p];
      int rm = 0;
      for (int k = 0; k < NQ; ++k) rm |= (int)(((col[k] >> p) & 1u) << k);
      T.rm[l][q] = rm;
    }
    for (int q = 0; q < NQ - 1; ++q) {
      const int pc = NQ - 1 - q, pt = NQ - 2 - q;
      for (int k = 0; k < NQ; ++k) col[k] ^= ((col[k] >> pc) & 1u) << pt;
      inv[pc] ^= inv[pt];
    }
  }
  for (int q = 0; q < NQ; ++q) {
    const int p = NQ - 1 - q;
    int rm = 0;
    for (int k = 0; k < NQ; ++k) rm |= (int)(((col[k] >> p) & 1u) << k);
    T.rout[q] = rm;
  }
  return T;
}
static constexpr MaskTab MT = build_masks();

// ---------------- compile-time utils ----------------
constexpr int cpar(int j, int m) { return __builtin_popcount((unsigned)(j & m)) & 1; }
constexpr int chb(int m) { return m ? (1 << (31 - __builtin_clz((unsigned)m))) : 0; }
constexpr bool dpp_ok(int d) { return d==1||d==2||d==3||d==7||d==8||d==15; }
constexpr int dpp_ctrl_for(int d) {
  return d==1?0xB1 : d==2?0x4E : d==3?0x1B : d==7?0x141 : d==8?0x128 : 0x140;
}
// 2-DPP compositions kept on VALU: 6=7^1, 12=15^3
constexpr bool synth2_ok(int d) { return d==6||d==12; }
constexpr int synth_a(int d) { return d==6?0x141 : 0x140; }
constexpr int synth_b(int d) { return d==6?0xB1  : 0x1B; }

template <int V> struct ic_ { static constexpr int v = V; };
template <int I, int N, typename F>
__device__ __forceinline__ void sfor(F&& f) {
  if constexpr (I < N) { f(ic_<I>{}); sfor<I + 1, N>(f); }
}

// ---------------- cross-lane primitives (verified rounds 4-10) -------
template <int CTRL>
__device__ __forceinline__ float dppf(float x) {
  return __int_as_float(__builtin_amdgcn_update_dpp(0, __float_as_int(x), CTRL, 0xF, 0xF, false));
}
template <int PAT>
__device__ __forceinline__ float swzf(float x) {
  return __int_as_float(__builtin_amdgcn_ds_swizzle(__float_as_int(x), PAT));
}

__device__ __forceinline__ f32x2 pfma(f32x2 t, f32x2 p, f32x2 s) {
  return __builtin_elementwise_fma(t, p, s);
}

// lane-parity base sign: odd parity -> +t, even -> -t (rounds 2-10 verified).
template <int MASK>
__device__ __forceinline__ float lane_sign(float t, int lane) {
  if constexpr (MASK == 0) return -t;
  else return (__popc(lane & MASK) & 1) ? t : -t;
}

// ---------------- one RY gate (tan form), 2-elem layout ----------------
template <int L, int Q>
__device__ __forceinline__ void gate(f32x2 (&s2)[64], float t, int lane) {
  constexpr int MK  = MT.mk[L][Q];
  constexpr int RM  = MT.rm[L][Q];
  constexpr int MKL = (MK >> 7) & 31;   // lane-xor (physical lane bits 0-4)
  constexpr int MKO = MK & 127;         // register+half xor (index bits 0-6)
  constexpr int RMH = (RM >> 7) & 31;
  constexpr int RMO = RM & 127;
  const float tl  = lane_sign<RMH>(t, lane);
  const float tln = -tl;
  constexpr int M2 = MKO >> 1;   // f32x2-register xor
  constexpr int HS = MKO & 1;    // half swap (index bit 0)

  if constexpr (MKL == 0 && HS == 0) {
    // ---- packed register butterfly; RMO even -> per-register uniform sign ----
    f32x2 tp; tp.x = tl;  tp.y = tl;
    f32x2 tn; tn.x = tln; tn.y = tln;
    constexpr int HB = chb(M2);
    sfor<0, 64>([&](auto RC) {
      constexpr int r0 = decltype(RC)::v;
      if constexpr ((r0 & HB) == 0) {
        constexpr int r1 = r0 ^ M2;
        const f32x2 A = s2[r0], B = s2[r1];
        s2[r0] = pfma(cpar(2*r0, RMO) ? tn : tp, B, A);
        s2[r1] = pfma(cpar(2*r1, RMO) ? tn : tp, A, B);
      }
    });
  } else if constexpr (MKL == 0) {
    // ---- half-swap register gates: scalar FMAs, no swap movs ----
    if constexpr (M2 == 0) {
      // mask == {bit0}: partner is the other component of the same register
      sfor<0, 64>([&](auto RC) {
        constexpr int r = decltype(RC)::v;
        const float ax = s2[r].x, ay = s2[r].y;
        s2[r].x = fmaf(cpar(2*r,   RMO) ? tln : tl, ay, ax);
        s2[r].y = fmaf(cpar(2*r+1, RMO) ? tln : tl, ax, ay);
      });
    } else {
      constexpr int HB = chb(M2);
      sfor<0, 64>([&](auto RC) {
        constexpr int r0 = decltype(RC)::v;
        if constexpr ((r0 & HB) == 0) {
          constexpr int r1 = r0 ^ M2;
          const float ax = s2[r0].x, ay = s2[r0].y;
          const float bx = s2[r1].x, by = s2[r1].y;
          s2[r0].x = fmaf(cpar(2*r0,   RMO) ? tln : tl, by, ax);
          s2[r0].y = fmaf(cpar(2*r0+1, RMO) ? tln : tl, bx, ay);
          s2[r1].x = fmaf(cpar(2*r1,   RMO) ? tln : tl, ay, bx);
          s2[r1].y = fmaf(cpar(2*r1+1, RMO) ? tln : tl, ax, by);
        }
      });
    }
  } else if constexpr (dpp_ok(MKL) || synth2_ok(MKL)) {
    // ---- DPP-path cross gates: scalar tied-dst form (DPPCombine target) ----
    // cross masks never contain bit 0 -> HS==0, RMO even -> uniform per reg
    auto D = [&](float x) -> float {
      if constexpr (dpp_ok(MKL)) return dppf<dpp_ctrl_for(MKL)>(x);
      else return dppf<synth_b(MKL)>(dppf<synth_a(MKL)>(x));
    };
    if constexpr (M2 == 0) {
      sfor<0, 64>([&](auto RC) {
        constexpr int r = decltype(RC)::v;
        const float sr = cpar(2*r, RMO) ? tln : tl;
        s2[r].x = fmaf(D(s2[r].x), sr, s2[r].x);
        s2[r].y = fmaf(D(s2[r].y), sr, s2[r].y);
      });
    } else {
      constexpr int HB = chb(M2);
      sfor<0, 64>([&](auto RC) {
        constexpr int r0 = decltype(RC)::v;
        if constexpr ((r0 & HB) == 0) {
          constexpr int r1 = r0 ^ M2;
          const float s0v = cpar(2*r0, RMO) ? tln : tl;
          const float s1v = cpar(2*r1, RMO) ? tln : tl;
          const float ax = s2[r0].x, ay = s2[r0].y;
          const float bx = s2[r1].x, by = s2[r1].y;
          s2[r0].x = fmaf(D(bx), s0v, ax);
          s2[r0].y = fmaf(D(by), s0v, ay);
          s2[r1].x = fmaf(D(ax), s1v, bx);
          s2[r1].y = fmaf(D(ay), s1v, by);
        }
      });
    }
  } else {
    // ---- DS swizzle cross gates (MKO==0 or even reg part; HS==0) ----
    constexpr int PAT = (MKL << 10) | 0x1F;
    f32x2 tp; tp.x = tl;  tp.y = tl;
    f32x2 tn; tn.x = tln; tn.y = tln;
    if constexpr (M2 == 0) {
      sfor<0, 64>([&](auto RC) {
        constexpr int r = decltype(RC)::v;
        f32x2 p; p.x = swzf<PAT>(s2[r].x); p.y = swzf<PAT>(s2[r].y);
        s2[r] = pfma(cpar(2*r, RMO) ? tn : tp, p, s2[r]);
      });
    } else {
      constexpr int HB = chb(M2);
      sfor<0, 64>([&](auto RC) {
        constexpr int r0 = decltype(RC)::v;
        if constexpr ((r0 & HB) == 0) {
          constexpr int r1 = r0 ^ M2;
          f32x2 pa; pa.x = swzf<PAT>(s2[r1].x); pa.y = swzf<PAT>(s2[r1].y);
          f32x2 pb; pb.x = swzf<PAT>(s2[r0].x); pb.y = swzf<PAT>(s2[r0].y);
          s2[r0] = pfma(cpar(2*r0, RMO) ? tn : tp, pa, s2[r0]);
          s2[r1] = pfma(cpar(2*r1, RMO) ? tn : tp, pb, s2[r1]);
        }
      });
    }
  }
}

template <int L, int Q>
__device__ __forceinline__ void round_rec(f32x2 (&s2)[64], const float (&t)[NQ], int lane) {
  if constexpr (Q < NQ) {
    gate<L, Q>(s2, t[Q], lane);
    round_rec<L, Q + 1>(s2, t, lane);
  }
}

__global__ __launch_bounds__(256, 2) void vqc_kernel(const float* __restrict__ ang,
                                                     const float* __restrict__ thetas,
                                                     float* __restrict__ out, int B) {
  const int tid  = blockIdx.x * blockDim.x + threadIdx.x;
  const int gw   = tid >> 6;          // wave index: elements 2gw, 2gw+1
  const int lane = tid & 63;
  const int l5   = lane & 31;
  const int elem = lane >> 5;
  const int row_store = 2 * gw + elem;
  const int row = (row_store < B) ? row_store : (B - 1);   // clamp, no early exit

  // ---- distributed angle prep -> per-wave LDS slab (round-10 verified) ----
  // slab per element (64 floats): [0..35] tan(l=1..3,q), [36..47] c0, [48..59] s0
  __shared__ float prep[4][2][64];
  const int wib = threadIdx.x >> 6;
  float* P = &prep[wib][elem][0];

  float csprod;
  {
    const int tau1 = l5;
    const int lq1 = (1 + tau1 / 12) * NQ + (tau1 % 12);
    float sn, cs;
    __sincosf(0.5f * (ang[row * NQ + (tau1 % 12)] + thetas[lq1]), &sn, &cs);
    P[tau1] = __fdividef(sn, cs);
    csprod = cs;
    if (l5 < 16) {
      const int tau2 = l5 + 32;
      if (tau2 < 36) {
        const int q2 = tau2 % 12;
        float sn2, cs2;
        __sincosf(0.5f * (ang[row * NQ + q2] + thetas[3 * NQ + q2]), &sn2, &cs2);
        P[tau2] = __fdividef(sn2, cs2);
        csprod *= cs2;
      } else {
        const int q2 = tau2 - 36;
        float sn2, cs2;
        __sincosf(0.5f * (ang[row * NQ + q2] + thetas[q2]), &sn2, &cs2);
        P[36 + q2] = cs2;
        P[48 + q2] = sn2;
      }
    }
    csprod *= dppf<0xB1>(csprod);
    csprod *= dppf<0x4E>(csprod);
    csprod *= swzf<(4 << 10) | 0x1F>(csprod);
    csprod *= dppf<0x128>(csprod);
    csprod *= swzf<(16 << 10) | 0x1F>(csprod);
  }
  const float Csq = csprod * csprod;
  __syncthreads();

  // vector read-back (broadcast reads, conflict-free)
  float t1[NQ], t2[NQ], t3[NQ], c0[NQ], s0[NQ];
  {
    const float4* P4 = (const float4*)P;
#define LD4(arr, base, idx) { float4 v = P4[idx]; arr[base]=v.x; arr[base+1]=v.y; arr[base+2]=v.z; arr[base+3]=v.w; }
    LD4(t1, 0, 0) LD4(t1, 4, 1) LD4(t1, 8, 2)
    LD4(t2, 0, 3) LD4(t2, 4, 4) LD4(t2, 8, 5)
    LD4(t3, 0, 6) LD4(t3, 4, 7) LD4(t3, 8, 8)
    LD4(c0, 0, 9) LD4(c0, 4, 10) LD4(c0, 8, 11)
    LD4(s0, 0, 12) LD4(s0, 4, 13) LD4(s0, 8, 14)
#undef LD4
  }

  // ---- layer 0 on |0..0>: per-element product state (rounds 9-10 verified) ----
  float flane = 1.0f;
  #pragma unroll
  for (int k = 0; k < 5; ++k) {
    flane *= ((l5 >> k) & 1) ? s0[4 - k] : c0[4 - k];
  }
  f32x2 s2[64];
  { f32x2 h0; h0.x = c0[11] * flane; h0.y = s0[11] * flane; s2[0] = h0; }
  #pragma unroll
  for (int k = 0; k < 6; ++k) {
    const int W = 1 << k;
    #pragma unroll
    for (int j = 0; j < 64; ++j) {
      if (j >= W) continue;
      s2[j + W] = s2[j] * s0[10 - k];
      s2[j]     = s2[j] * c0[10 - k];
    }
  }

  // ---- layers 1-3 (tan form) ----
  round_rec<1, 0>(s2, t1, lane);
  round_rec<2, 0>(s2, t2, lane);
  round_rec<3, 0>(s2, t3, lane);

  // probabilities (unscaled, packed)
  #pragma unroll
  for (int r = 0; r < 64; ++r) s2[r] = s2[r] * s2[r];

  // Walsh-Hadamard over the 7 register-dim bits
  #pragma unroll
  for (int r = 0; r < 64; ++r) {
    const float u = s2[r].x, v = s2[r].y;
    s2[r].x = u + v;
    s2[r].y = u - v;
  }
  #pragma unroll
  for (int b = 0; b < 6; ++b) {
    const int W = 1 << b;
    #pragma unroll
    for (int r0 = 0; r0 < 64; ++r0) {
      if (r0 & W) continue;
      const int r1 = r0 | W;
      const f32x2 u = s2[r0], v = s2[r1];
      s2[r0] = u + v;
      s2[r1] = u - v;
    }
  }

  // ---- epilogue: 12 signed reductions over lane bits 0-4 (per element) ----
  sfor<0, NQ>([&](auto QC) {
    constexpr int q   = decltype(QC)::v;
    constexpr int RM  = MT.rout[q];
    constexpr int RMH = (RM >> 7) & 31;
    constexpr int RMO = RM & 127;
    float v = (RMO & 1) ? s2[RMO >> 1].y : s2[RMO >> 1].x;
    if constexpr (RMH != 0) {
      const int sx = (__popc(lane & RMH) & 1) << 31;  // odd lane parity -> minus
      v = __int_as_float(__float_as_int(v) ^ sx);
    }
    v += dppf<0xB1>(v);               // xor1
    v += dppf<0x4E>(v);               // xor2
    v += swzf<(4 << 10) | 0x1F>(v);   // xor4
    v += dppf<0x128>(v);              // xor8
    v += swzf<(16 << 10) | 0x1F>(v);  // xor16 (within 32-lane group)
    if (l5 == 0 && row_store < B) out[row_store * NQ + q] = v * Csq;
  });
}

extern "C" void kernel_launch(void* const* d_in, const int* in_sizes, int n_in,
                              void* d_out, int out_size, void* d_ws, size_t ws_size,
                              hipStream_t stream) {
  const float* ang    = (const float*)d_in[0];
  const float* thetas = (const float*)d_in[1];
  float* out          = (float*)d_out;
  const int B = in_sizes[0] / NQ;
  const int waves = (B + 1) / 2;       // 2 elements per wave
  const int threads = 256;
  const int blocks = (waves * 64 + threads - 1) / threads;
  hipLaunchKernelGGL(vqc_kernel, dim3(blocks), dim3(threads), 0, stream,
                     ang, thetas, out, B);
}